// Round 10
// baseline (362.679 us; speedup 1.0000x reference)
//
#include <hip/hip_runtime.h>
#include <hip/hip_bf16.h>

#define BATCH 2
#define SEQLEN 2048
#define DMODEL 256
#define DINNER 512
#define NHEADS 8
#define HEADDIM 64
#define DSTATE 64
#define CONVDIM 640
#define DINPROJ 1160
#define NTOK (BATCH*SEQLEN)
#define Q 64
#define NCH (SEQLEN/Q)
#define NPAD_IN 1216
#define TS 72
#define NBLK 512

typedef short v8s __attribute__((ext_vector_type(8)));
typedef float v4f __attribute__((ext_vector_type(4)));

__device__ __forceinline__ unsigned short f2bf(float f){
    __hip_bfloat16 h = __float2bfloat16(f);
    return *reinterpret_cast<unsigned short*>(&h);
}
__device__ __forceinline__ float bf2f(unsigned short u){
    unsigned int x = ((unsigned int)u) << 16;
    return __uint_as_float(x);
}

// device-scope grid barrier: each barrier index used exactly once per launch.
// counters zeroed by hipMemsetAsync before the kernel. Release: threadfence
// (L2 writeback on gfx94x+) + atomicAdd. Spin: agent-scope atomic load
// (bypasses non-coherent per-XCD L2). Acquire: threadfence (L1/L2 inv).
__device__ __forceinline__ void gbar(unsigned* sync, int idx){
    __syncthreads();
    if(threadIdx.x==0){
        __threadfence();
        atomicAdd(&sync[idx*16], 1u);
        while(__hip_atomic_load(&sync[idx*16], __ATOMIC_RELAXED, __HIP_MEMORY_SCOPE_AGENT) < (unsigned)NBLK)
            __builtin_amdgcn_s_sleep(8);
        __threadfence();
    }
    __syncthreads();
}

__global__ __launch_bounds__(256, 2) void k_mega(
        const float* __restrict__ hid, const float* __restrict__ nw, const float* __restrict__ nb,
        const float* __restrict__ Win, const float* __restrict__ conv_w, const float* __restrict__ conv_b,
        const float* __restrict__ dt_bias, const float* __restrict__ A_log, const float* __restrict__ D_param,
        const float* __restrict__ rms_w, const float* __restrict__ Wout,
        unsigned* __restrict__ sync,
        float* __restrict__ contrib, float* __restrict__ Larr, float* __restrict__ decayA,
        unsigned short* __restrict__ zxb, unsigned short* __restrict__ yw16,
        unsigned short* __restrict__ Sb, unsigned short* __restrict__ Ccv,
        unsigned short* __restrict__ Xb, unsigned short* __restrict__ Wti, unsigned short* __restrict__ Wto,
        float* __restrict__ out, float* __restrict__ res){
    int bid = blockIdx.x;
    int t = threadIdx.x;
    int lane = t & 63, w = t >> 6;
    int lanelow = lane & 15, quad = lane >> 4;

    __shared__ __align__(16) union SM {
        struct { float xs[16][DMODEL]; } a;                                   // 16 KB
        struct { unsigned short As[128*40]; unsigned short Bs[64*40]; } b;    // 15 KB
        struct { unsigned short Cb[64*TS], Bb[64*TS], BtW[64*TS], Xt[64*TS], Gbuf[64*TS];
                 float Ls[Q], dts[Q], wch[Q]; } c;                            // 46.8 KB
        struct { unsigned short G[16*528]; float wsum[4][16]; float rstd[16]; } e; // 17.2 KB
    } sm;

    // ================= Phase A: LayerNorm (+residual) & weight conversion =================
    if(bid < 256){
        int tok0 = bid*16;
        for(int i=0;i<16;i++){
            int idx = i*256+t; int j = idx>>8, cc = idx&255;
            float v = hid[(size_t)(tok0+j)*DMODEL + cc];
            sm.a.xs[j][cc] = v;
            res[(size_t)(tok0+j)*DMODEL + cc] = v;
        }
        __syncthreads();
        int g = t>>4, il = t&15;
        float sum=0.f, sumsq=0.f;
        for(int i=0;i<16;i++){ float v = sm.a.xs[g][il*16+i]; sum += v; sumsq += v*v; }
        #pragma unroll
        for(int m=1;m<16;m<<=1){ sum += __shfl_xor(sum,m); sumsq += __shfl_xor(sumsq,m); }
        float mu   = sum*(1.f/256.f);
        float var  = sumsq*(1.f/256.f) - mu*mu;
        float rstd = rsqrtf(var + 1e-5f);
        for(int i=0;i<16;i++){
            int cc = il*16+i;
            sm.a.xs[g][cc] = (sm.a.xs[g][cc]-mu)*rstd*nw[cc] + nb[cc];
        }
        __syncthreads();
        for(int i=0;i<16;i++){
            int idx = i*256+t; int j = idx>>8, cc = idx&255;
            Xb[(size_t)(tok0+j)*DMODEL + cc] = f2bf(sm.a.xs[j][cc]);
        }
    }
    if(bid >= 144){
        int u = bid - 144;
        if(u < 304){
            int n0 = u*4, k = t;
            #pragma unroll
            for(int i=0;i<4;i++){
                int n = n0+i;
                float v = (n < DINPROJ) ? Win[(size_t)k*DINPROJ + n] : 0.f;
                Wti[(size_t)n*DMODEL + k] = f2bf(v);
            }
        } else {
            int n0 = (u-304)*4;
            #pragma unroll
            for(int kk=0;kk<2;kk++){
                int k = t + kk*256;
                float rw = rms_w[k];
                #pragma unroll
                for(int i=0;i<4;i++){
                    int n = n0+i;
                    Wto[(size_t)n*DINNER + k] = f2bf(Wout[(size_t)k*DMODEL + n] * rw);
                }
            }
        }
    }
    gbar(sync, 0);

    // ================= Phase B: in-proj MFMA GEMM (bf16 out) =================
    for(int u = bid; u < 608; u += NBLK){
        int tok0 = (u & 31) * 128;
        int n0   = (u >> 5) * 64;
        v4f acc[2][4];
        #pragma unroll
        for(int mi=0;mi<2;mi++)
            #pragma unroll
            for(int ni=0;ni<4;ni++)
                acc[mi][ni] = (v4f){0.f,0.f,0.f,0.f};
        for(int k0=0; k0<DMODEL; k0+=32){
            __syncthreads();
            #pragma unroll
            for(int cc=0; cc<2; cc++){
                int c = t + cc*256;
                int row = c>>2, off = c&3;
                uint4 v = *(const uint4*)(Xb + (size_t)(tok0+row)*DMODEL + k0 + off*8);
                *(uint4*)&sm.b.As[row*40 + off*8] = v;
            }
            {
                int row = t>>2, off = t&3;
                uint4 v = *(const uint4*)(Wti + (size_t)(n0+row)*DMODEL + k0 + off*8);
                *(uint4*)&sm.b.Bs[row*40 + off*8] = v;
            }
            __syncthreads();
            v8s a0 = *(const v8s*)&sm.b.As[(w*32 +      lanelow)*40 + quad*8];
            v8s a1 = *(const v8s*)&sm.b.As[(w*32 + 16 + lanelow)*40 + quad*8];
            v8s b[4];
            #pragma unroll
            for(int ni=0;ni<4;ni++)
                b[ni] = *(const v8s*)&sm.b.Bs[(ni*16 + lanelow)*40 + quad*8];
            #pragma unroll
            for(int ni=0;ni<4;ni++){
                acc[0][ni] = __builtin_amdgcn_mfma_f32_16x16x32_bf16(a0, b[ni], acc[0][ni], 0,0,0);
                acc[1][ni] = __builtin_amdgcn_mfma_f32_16x16x32_bf16(a1, b[ni], acc[1][ni], 0,0,0);
            }
        }
        #pragma unroll
        for(int mi=0;mi<2;mi++){
            #pragma unroll
            for(int ni=0;ni<4;ni++){
                int col = n0 + ni*16 + lanelow;
                if(col < DINPROJ){
                    #pragma unroll
                    for(int r=0;r<4;r++){
                        int row = tok0 + w*32 + mi*16 + quad*4 + r;
                        zxb[(size_t)row*DINPROJ + col] = f2bf(acc[mi][ni][r]);
                    }
                }
            }
        }
        __syncthreads();
    }
    gbar(sync, 1);

    // ================= Phase C: conv + chunk-local SSD (512 units, 1:1) =================
    {
        int c = bid & 31, h = (bid>>5)&7, b = bid>>8;
        int l0 = c*Q;
        int bh = b*NHEADS + h;
        const unsigned short* zbase = zxb + (size_t)(b*SEQLEN + l0)*DINPROJ;
        if(t < Q){
            float v = bf2f(zbase[(size_t)t*DINPROJ + (DINPROJ-NHEADS) + h]) + dt_bias[h];
            float dt = (v > 20.f) ? v : log1pf(__expf(v));
            float A  = -__expf(A_log[h]);
            float ld = dt*A;
            #pragma unroll
            for(int off=1; off<64; off<<=1){
                float u = __shfl_up(ld, off);
                if(lane >= off) ld += u;
            }
            sm.c.Ls[t] = ld; sm.c.dts[t] = dt;
        }
        __syncthreads();
        float L63 = sm.c.Ls[Q-1];
        if(t < Q) sm.c.wch[t] = __expf(L63 - sm.c.Ls[t]) * sm.c.dts[t];
        __syncthreads();
        unsigned short* CcP = Ccv + ((size_t)b*NCH + c)*4096;
        for(int i=0;i<12;i++){
            int u = t + 256*i;
            int st = u & 63, c4 = u >> 6, ch = c4*4;
            int gcol = (ch < 64) ? (DINNER + h*HEADDIM + ch) : (2*DINNER + (ch-64));
            const unsigned short* colp = zbase + (ptrdiff_t)st*DINPROJ + gcol;
            float xk[4][4];
            #pragma unroll
            for(int k=0;k<4;k++){
                int l = l0 + st + k - 3;
                ushort4 v;
                if(l >= 0) v = *(const ushort4*)(colp - (ptrdiff_t)(3-k)*DINPROJ);
                else { v.x=0; v.y=0; v.z=0; v.w=0; }
                xk[k][0]=bf2f(v.x); xk[k][1]=bf2f(v.y); xk[k][2]=bf2f(v.z); xk[k][3]=bf2f(v.w);
            }
            float wst = sm.c.wch[st];
            #pragma unroll
            for(int j=0;j<4;j++){
                int chj = ch+j;
                int cc = (chj<64) ? (h*HEADDIM + chj) : (448 + chj);
                float4 wv = *(const float4*)&conv_w[cc*4];
                float acc = conv_b[cc] + wv.x*xk[0][j] + wv.y*xk[1][j] + wv.z*xk[2][j] + wv.w*xk[3][j];
                float sv = acc/(1.f+__expf(-acc));
                if(chj < 64){
                    sm.c.Xt[chj*TS + st] = f2bf(sv);
                } else if(chj < 128){
                    int n = chj-64;
                    sm.c.Bb[st*TS + n]  = f2bf(sv);
                    sm.c.BtW[n*TS + st] = f2bf(sv*wst);
                } else {
                    int n = chj-128;
                    unsigned short sb16 = f2bf(sv);
                    sm.c.Cb[st*TS + n] = sb16;
                    if(h==0) CcP[st*64 + n] = sb16;
                }
            }
        }
        __syncthreads();
        v4f g[4];
        #pragma unroll
        for(int nt=0;nt<4;nt++) g[nt] = (v4f){0.f,0.f,0.f,0.f};
        #pragma unroll
        for(int kk=0;kk<2;kk++){
            v8s a = *(const v8s*)&sm.c.Cb[(w*16+lanelow)*TS + kk*32 + quad*8];
            #pragma unroll
            for(int nt=0;nt<4;nt++){
                v8s bb = *(const v8s*)&sm.c.Bb[(nt*16+lanelow)*TS + kk*32 + quad*8];
                g[nt] = __builtin_amdgcn_mfma_f32_16x16x32_bf16(a, bb, g[nt], 0,0,0);
            }
        }
        float Lrow[4];
        #pragma unroll
        for(int r=0;r<4;r++) Lrow[r] = sm.c.Ls[w*16 + quad*4 + r];
        #pragma unroll
        for(int nt=0;nt<4;nt++){
            int col = nt*16 + lanelow;
            float Lc = sm.c.Ls[col], dtc = sm.c.dts[col];
            #pragma unroll
            for(int r=0;r<4;r++){
                int rowg = w*16 + quad*4 + r;
                float val = (col <= rowg) ? g[nt][r] * __expf(Lrow[r]-Lc) * dtc : 0.f;
                sm.c.Gbuf[rowg*TS + col] = f2bf(val);
            }
        }
        __syncthreads();
        v4f ya[4], sa[4];
        #pragma unroll
        for(int nt=0;nt<4;nt++){ ya[nt]=(v4f){0.f,0.f,0.f,0.f}; sa[nt]=(v4f){0.f,0.f,0.f,0.f}; }
        #pragma unroll
        for(int kk=0;kk<2;kk++){
            v8s ag = *(const v8s*)&sm.c.Gbuf[(w*16+lanelow)*TS + kk*32 + quad*8];
            v8s ax = *(const v8s*)&sm.c.Xt[(w*16+lanelow)*TS + kk*32 + quad*8];
            #pragma unroll
            for(int nt=0;nt<4;nt++){
                v8s bx = *(const v8s*)&sm.c.Xt[(nt*16+lanelow)*TS + kk*32 + quad*8];
                v8s bw = *(const v8s*)&sm.c.BtW[(nt*16+lanelow)*TS + kk*32 + quad*8];
                ya[nt] = __builtin_amdgcn_mfma_f32_16x16x32_bf16(ag, bx, ya[nt], 0,0,0);
                sa[nt] = __builtin_amdgcn_mfma_f32_16x16x32_bf16(ax, bw, sa[nt], 0,0,0);
            }
        }
        float Dp = D_param[h];
        #pragma unroll
        for(int nt=0;nt<4;nt++){
            int col = nt*16 + lanelow;
            #pragma unroll
            for(int r=0;r<4;r++){
                int i = w*16 + quad*4 + r;
                float xval = bf2f(sm.c.Xt[col*TS + i]);
                yw16[((size_t)b*SEQLEN + l0 + i)*DINNER + h*HEADDIM + col] = f2bf(ya[nt][r] + Dp*xval);
                contrib[(((size_t)bh*NCH + c)*64 + i)*64 + col] = sa[nt][r];
            }
        }
        if(t < Q) Larr[((size_t)bh*NCH + c)*Q + t] = sm.c.Ls[t];
        if(t == 0) decayA[bh*NCH + c] = __expf(L63);
    }
    gbar(sync, 2);

    // ================= Phase D: inter-chunk state scan =================
    if(t < 128){
        int eg = bid*128 + t;
        int bh = eg >> 12;
        int e  = eg & 4095;
        const size_t base = (size_t)bh*NCH*4096 + e;
        float vals[NCH];
        #pragma unroll
        for(int c=0;c<NCH;c++) vals[c] = contrib[base + (size_t)c*4096];
        float s = 0.f;
        #pragma unroll
        for(int c=0;c<NCH;c++){
            Sb[base + (size_t)c*4096] = f2bf(s);
            s = fmaf(s, decayA[bh*NCH + c], vals[c]);
        }
    }
    gbar(sync, 3);

    // ================= Phase E: inter-chunk y + gate + RMS + out-proj =================
    if(bid < 256){
        int b = bid >> 7, tg = bid & 127;
        int c = tg >> 2, q16 = tg & 3;
        size_t tok0 = (size_t)b*SEQLEN + c*Q + q16*16;
        float gg[2][4][4];
        float sq[4] = {0.f,0.f,0.f,0.f};
        const unsigned short* Cp = Ccv + ((size_t)b*NCH + c)*4096;
        #pragma unroll
        for(int hh=0; hh<2; hh++){
            int h = w*2 + hh;
            int bh = b*NHEADS + h;
            const unsigned short* Sp = Sb + ((size_t)bh*NCH + c)*4096;
            const float* Lp = Larr + ((size_t)bh*NCH + c)*Q;
            v8s a0 = *(const v8s*)(Cp + (q16*16+lanelow)*64 + quad*8);
            v8s a1 = *(const v8s*)(Cp + (q16*16+lanelow)*64 + 32 + quad*8);
            float eL[4];
            #pragma unroll
            for(int r=0;r<4;r++) eL[r] = __expf(Lp[q16*16 + quad*4 + r]);
            #pragma unroll
            for(int nt=0;nt<4;nt++){
                v8s s0 = *(const v8s*)(Sp + (nt*16+lanelow)*64 + quad*8);
                v8s s1 = *(const v8s*)(Sp + (nt*16+lanelow)*64 + 32 + quad*8);
                v4f acc = (v4f){0.f,0.f,0.f,0.f};
                acc = __builtin_amdgcn_mfma_f32_16x16x32_bf16(a0, s0, acc, 0,0,0);
                acc = __builtin_amdgcn_mfma_f32_16x16x32_bf16(a1, s1, acc, 0,0,0);
                int col = h*HEADDIM + nt*16 + lanelow;
                #pragma unroll
                for(int r=0;r<4;r++){
                    int i = quad*4 + r;
                    size_t tok = tok0 + i;
                    float yv = acc[r]*eL[r] + bf2f(yw16[tok*DINNER + col]);
                    float z  = bf2f(zxb[tok*DINPROJ + col]);
                    float gv = yv * (z/(1.f+__expf(-z)));
                    gg[hh][nt][r] = gv;
                    sq[r] += gv*gv;
                }
            }
        }
        #pragma unroll
        for(int hh=0;hh<2;hh++)
            #pragma unroll
            for(int nt=0;nt<4;nt++)
                #pragma unroll
                for(int r=0;r<4;r++)
                    sm.e.G[(quad*4+r)*528 + (w*2+hh)*64 + nt*16 + lanelow] = f2bf(gg[hh][nt][r]);
        #pragma unroll
        for(int r=0;r<4;r++){
            float v = sq[r];
            #pragma unroll
            for(int m=1;m<16;m<<=1) v += __shfl_xor(v, m);
            sq[r] = v;
        }
        if(lanelow==0){
            #pragma unroll
            for(int r=0;r<4;r++) sm.e.wsum[w][quad*4+r] = sq[r];
        }
        __syncthreads();
        if(t < 16)
            sm.e.rstd[t] = rsqrtf((sm.e.wsum[0][t]+sm.e.wsum[1][t]+sm.e.wsum[2][t]+sm.e.wsum[3][t])*(1.f/512.f) + 1e-5f);
        __syncthreads();
        v4f acc[4];
        #pragma unroll
        for(int nt=0;nt<4;nt++) acc[nt] = (v4f){0.f,0.f,0.f,0.f};
        for(int ki=0; ki<16; ki++){
            v8s a = *(const v8s*)&sm.e.G[lanelow*528 + ki*32 + quad*8];
            #pragma unroll
            for(int nt=0;nt<4;nt++){
                v8s bfr = *(const v8s*)(Wto + (size_t)(w*64 + nt*16 + lanelow)*DINNER + ki*32 + quad*8);
                acc[nt] = __builtin_amdgcn_mfma_f32_16x16x32_bf16(a, bfr, acc[nt], 0,0,0);
            }
        }
        float rs[4];
        #pragma unroll
        for(int r=0;r<4;r++) rs[r] = sm.e.rstd[quad*4+r];
        #pragma unroll
        for(int nt=0;nt<4;nt++){
            int col = w*64 + nt*16 + lanelow;
            #pragma unroll
            for(int r=0;r<4;r++)
                out[(tok0 + quad*4 + r)*DMODEL + col] = acc[nt][r]*rs[r];
        }
    }
}

extern "C" void kernel_launch(void* const* d_in, const int* in_sizes, int n_in,
                              void* d_out, int out_size, void* d_ws, size_t ws_size,
                              hipStream_t stream) {
    const float* hid     = (const float*)d_in[0];
    const float* norm_w  = (const float*)d_in[1];
    const float* norm_b  = (const float*)d_in[2];
    const float* Win     = (const float*)d_in[3];
    const float* conv_w  = (const float*)d_in[4];
    const float* conv_b  = (const float*)d_in[5];
    const float* dt_bias = (const float*)d_in[6];
    const float* A_log   = (const float*)d_in[7];
    const float* D_param = (const float*)d_in[8];
    const float* rms_w   = (const float*)d_in[9];
    const float* Wout    = (const float*)d_in[10];

    unsigned* sync = (unsigned*)d_ws;                              // 4 barriers x 64B
    float* contrib = (float*)d_ws + 256;                           // 16*32*4096 f
    float* Larr    = contrib + (size_t)16*NCH*4096;                // 32768 f
    float* decayA  = Larr + (size_t)16*NCH*Q;                      // 512 f
    unsigned short* zxb  = (unsigned short*)(decayA + 512);        // 4096*1160
    unsigned short* yw16 = zxb + (size_t)NTOK*DINPROJ;             // 4096*512
    unsigned short* Sb   = yw16 + (size_t)NTOK*DINNER;             // 16*32*4096
    unsigned short* Ccv  = Sb + (size_t)16*NCH*4096;               // 2*32*4096
    unsigned short* Xb   = Ccv + (size_t)BATCH*NCH*4096;           // 4096*256
    unsigned short* Wti  = Xb + (size_t)NTOK*DMODEL;               // 1216*256
    unsigned short* Wto  = Wti + (size_t)NPAD_IN*DMODEL;           // 256*512

    float* out = (float*)d_out;
    float* res = out + (size_t)NTOK*DMODEL;

    hipMemsetAsync(sync, 0, 4*16*sizeof(unsigned), stream);
    k_mega<<<NBLK, 256, 0, stream>>>(hid, norm_w, norm_b, Win, conv_w, conv_b,
                                     dt_bias, A_log, D_param, rms_w, Wout,
                                     sync, contrib, Larr, decayA, zxb, yw16, Sb, Ccv,
                                     Xb, Wti, Wto, out, res);
}

// Round 11
// 138.783 us; speedup vs baseline: 2.6133x; 2.6133x over previous
//
#include <hip/hip_runtime.h>
#include <hip/hip_bf16.h>

#define BATCH 2
#define SEQLEN 2048
#define DMODEL 256
#define DINNER 512
#define NHEADS 8
#define HEADDIM 64
#define DSTATE 64
#define CONVDIM 640
#define DINPROJ 1160
#define NTOK (BATCH*SEQLEN)
#define Q 64
#define NCH (SEQLEN/Q)
#define NPAD_IN 1216
#define TS 72          // bf16 MFMA tile stride (b128 reads at stride 36 words are conflict-free)
#define RS3 196        // conv slab stride: 392B row stride (8B-aligned), 98-word stride -> conflict-free b64

typedef short v8s __attribute__((ext_vector_type(8)));
typedef float v4f __attribute__((ext_vector_type(4)));

__device__ __forceinline__ unsigned short f2bf(float f){
    __hip_bfloat16 h = __float2bfloat16(f);
    return *reinterpret_cast<unsigned short*>(&h);
}
__device__ __forceinline__ float bf2f(unsigned short u){
    unsigned int x = ((unsigned int)u) << 16;
    return __uint_as_float(x);
}

// ---------------- prep: LayerNorm (+residual) and weight conversion, block-partitioned ----------------
__global__ __launch_bounds__(256) void k_prep(
        const float* __restrict__ hid, const float* __restrict__ nw, const float* __restrict__ nb,
        const float* __restrict__ Win, const float* __restrict__ Wout,
        float* __restrict__ res, unsigned short* __restrict__ Xb,
        unsigned short* __restrict__ Wti, unsigned short* __restrict__ Wto){
    int bx = blockIdx.x;
    int t = threadIdx.x;
    if(bx < 256){
        __shared__ float xs[16][DMODEL];
        int tok0 = bx*16;
        for(int i=0;i<16;i++){
            int idx = i*256+t; int j = idx>>8, c = idx&255;
            float v = hid[(size_t)(tok0+j)*DMODEL + c];
            xs[j][c] = v;
            res[(size_t)(tok0+j)*DMODEL + c] = v;
        }
        __syncthreads();
        int g = t>>4, il = t&15;
        float sum=0.f, sumsq=0.f;
        for(int i=0;i<16;i++){ float v = xs[g][il*16+i]; sum += v; sumsq += v*v; }
        #pragma unroll
        for(int m=1;m<16;m<<=1){ sum += __shfl_xor(sum,m); sumsq += __shfl_xor(sumsq,m); }
        float mu   = sum*(1.f/256.f);
        float var  = sumsq*(1.f/256.f) - mu*mu;
        float rstd = rsqrtf(var + 1e-5f);
        for(int i=0;i<16;i++){
            int c = il*16+i;
            xs[g][c] = (xs[g][c]-mu)*rstd*nw[c] + nb[c];
        }
        __syncthreads();
        for(int i=0;i<16;i++){
            int idx = i*256+t; int j = idx>>8, c = idx&255;
            Xb[(size_t)(tok0+j)*DMODEL + c] = f2bf(xs[j][c]);
        }
    } else if(bx < 256 + NPAD_IN/4){
        int n0 = (bx-256)*4, k = t;
        #pragma unroll
        for(int i=0;i<4;i++){
            int n = n0+i;
            float v = (n < DINPROJ) ? Win[(size_t)k*DINPROJ + n] : 0.f;
            Wti[(size_t)n*DMODEL + k] = f2bf(v);
        }
    } else {
        int n0 = (bx - 256 - NPAD_IN/4)*4;
        #pragma unroll
        for(int kk=0;kk<2;kk++){
            int k = t + kk*256;
            #pragma unroll
            for(int i=0;i<4;i++){
                int n = n0+i;
                Wto[(size_t)n*DINNER + k] = f2bf(Wout[(size_t)k*DMODEL + n]);
            }
        }
    }
}

// ---------------- MFMA bf16 GEMM: C(MxN) = A(MxK,bf16) @ Bt(NxK,bf16)^T ----------------
template<int BF16OUT>
__global__ __launch_bounds__(256) void k_gemm(
        const unsigned short* __restrict__ A, const unsigned short* __restrict__ Bt,
        float* __restrict__ Cf, unsigned short* __restrict__ Cb, int K, int Ncols){
    __shared__ __align__(16) unsigned short As[128*40];
    __shared__ __align__(16) unsigned short Bs[64*40];
    int t = threadIdx.x;
    int lane = t & 63, w = t >> 6;
    int lanelow = lane & 15, quad = lane >> 4;
    int tok0 = blockIdx.x * 128;
    int n0   = blockIdx.y * 64;
    v4f acc[2][4];
    #pragma unroll
    for(int mi=0;mi<2;mi++)
        #pragma unroll
        for(int ni=0;ni<4;ni++)
            acc[mi][ni] = (v4f){0.f,0.f,0.f,0.f};
    for(int k0=0; k0<K; k0+=32){
        __syncthreads();
        #pragma unroll
        for(int cc=0; cc<2; cc++){
            int c = t + cc*256;
            int row = c>>2, off = c&3;
            uint4 v = *(const uint4*)(A + (size_t)(tok0+row)*K + k0 + off*8);
            *(uint4*)&As[row*40 + off*8] = v;
        }
        {
            int row = t>>2, off = t&3;
            uint4 v = *(const uint4*)(Bt + (size_t)(n0+row)*K + k0 + off*8);
            *(uint4*)&Bs[row*40 + off*8] = v;
        }
        __syncthreads();
        v8s a0 = *(const v8s*)&As[(w*32 +      lanelow)*40 + quad*8];
        v8s a1 = *(const v8s*)&As[(w*32 + 16 + lanelow)*40 + quad*8];
        v8s b[4];
        #pragma unroll
        for(int ni=0;ni<4;ni++)
            b[ni] = *(const v8s*)&Bs[(ni*16 + lanelow)*40 + quad*8];
        #pragma unroll
        for(int ni=0;ni<4;ni++){
            acc[0][ni] = __builtin_amdgcn_mfma_f32_16x16x32_bf16(a0, b[ni], acc[0][ni], 0,0,0);
            acc[1][ni] = __builtin_amdgcn_mfma_f32_16x16x32_bf16(a1, b[ni], acc[1][ni], 0,0,0);
        }
    }
    #pragma unroll
    for(int mi=0;mi<2;mi++){
        #pragma unroll
        for(int ni=0;ni<4;ni++){
            int col = n0 + ni*16 + lanelow;
            if(col < Ncols){
                #pragma unroll
                for(int r=0;r<4;r++){
                    int row = tok0 + w*32 + mi*16 + quad*4 + r;
                    if(BF16OUT) Cb[(size_t)row*Ncols + col] = f2bf(acc[mi][ni][r]);
                    else        Cf[(size_t)row*Ncols + col] = acc[mi][ni][r];
                }
            }
        }
    }
}

// ---------------- fused conv + chunk-local SSD via MFMA; conv via coalesced LDS slabs ----------------
// grid 512 = b x h x chunk; 256 threads = 4 waves. LDS 54.3 KB -> 3 blocks/CU.
__global__ __launch_bounds__(256) void k_chunk1(
        const unsigned short* __restrict__ zxb, const float* __restrict__ conv_w, const float* __restrict__ conv_b,
        const float* __restrict__ dt_bias, const float* __restrict__ A_log, const float* __restrict__ D_param,
        unsigned short* __restrict__ yw16, unsigned short* __restrict__ contrib16,
        float* __restrict__ Larr, float* __restrict__ decayArr, unsigned short* __restrict__ Ccv){
    int blk = blockIdx.x;
    int c = blk & 31, h = (blk>>5)&7, b = blk>>8;
    int t = threadIdx.x;
    int lane = t & 63, w = t >> 6;
    int lanelow = lane & 15, quad = lane >> 4;
    __shared__ __align__(16) unsigned short Cb[64*TS];
    __shared__ __align__(16) unsigned short Bb[64*TS];
    __shared__ __align__(16) unsigned short BtW[64*TS];
    __shared__ __align__(16) unsigned short Xt[64*TS];
    __shared__ __align__(16) unsigned short Gbuf[64*TS];
    __shared__ __align__(16) unsigned short raw[19*RS3];
    __shared__ float Ls[Q], dts[Q], wch[Q];
    int l0 = c*Q;
    int bh = b*NHEADS + h;
    const unsigned short* zbase = zxb + (size_t)(b*SEQLEN + l0)*DINPROJ;
    // ---- dt softplus + ldA cumsum (wave 0) ----
    if(t < Q){
        float v = bf2f(zbase[(size_t)t*DINPROJ + (DINPROJ-NHEADS) + h]) + dt_bias[h];
        float dt = (v > 20.f) ? v : log1pf(__expf(v));
        float A  = -__expf(A_log[h]);
        float ld = dt*A;
        #pragma unroll
        for(int off=1; off<64; off<<=1){
            float u = __shfl_up(ld, off);
            if(lane >= off) ld += u;
        }
        Ls[t] = ld; dts[t] = dt;
    }
    __syncthreads();
    float L63 = Ls[Q-1];
    if(t < Q) wch[t] = __expf(L63 - Ls[t]) * dts[t];
    // ---- conv(K=4) + SiLU via 4 coalesced LDS slabs of 16 tokens ----
    unsigned short* CcP = Ccv + ((size_t)b*NCH + c)*4096;
    for(int s=0; s<4; s++){
        __syncthreads();
        // stage 19 rows x 192 ch (ushort4 = 8B per lane, coalesced along channels)
        #pragma unroll
        for(int i=0;i<4;i++){
            int u = t + 256*i;
            if(u < 19*48){
                int row = u/48, seg = u%48;
                int l = l0 + s*16 - 3 + row;
                int gcol = (seg<16) ? (DINNER + h*HEADDIM + seg*4) : (2*DINNER + (seg-16)*4);
                ushort4 v;
                if(l >= 0) v = *(const ushort4*)(zxb + ((size_t)b*SEQLEN + l)*DINPROJ + gcol);
                else { v.x=0; v.y=0; v.z=0; v.w=0; }
                *(ushort4*)&raw[row*RS3 + seg*4] = v;
            }
        }
        __syncthreads();
        // compute: 16 tokens x 48 ch-groups = 768 units
        #pragma unroll
        for(int i=0;i<3;i++){
            int u = t + 256*i;
            int stl = u & 15, grp = u >> 4;      // grp 0..47
            int st = s*16 + stl;
            int ch = grp*4;                       // 0..188
            float xk[4][4];
            #pragma unroll
            for(int k=0;k<4;k++){
                ushort4 v = *(const ushort4*)&raw[(stl+k)*RS3 + ch];
                xk[k][0]=bf2f(v.x); xk[k][1]=bf2f(v.y); xk[k][2]=bf2f(v.z); xk[k][3]=bf2f(v.w);
            }
            float wst = wch[st];
            #pragma unroll
            for(int j=0;j<4;j++){
                int chj = ch+j;
                int cc = (chj<64) ? (h*HEADDIM + chj) : (448 + chj);
                float4 wv = *(const float4*)&conv_w[cc*4];
                float acc = conv_b[cc] + wv.x*xk[0][j] + wv.y*xk[1][j] + wv.z*xk[2][j] + wv.w*xk[3][j];
                float sv = acc/(1.f+__expf(-acc));
                if(chj < 64){
                    Xt[chj*TS + st] = f2bf(sv);
                } else if(chj < 128){
                    int n = chj-64;
                    Bb[st*TS + n]  = f2bf(sv);
                    BtW[n*TS + st] = f2bf(sv*wst);
                } else {
                    int n = chj-128;
                    unsigned short sb16 = f2bf(sv);
                    Cb[st*TS + n] = sb16;
                    if(h==0) CcP[st*64 + n] = sb16;
                }
            }
        }
    }
    __syncthreads();
    // ---- G = C.B^T ----
    v4f g[4];
    #pragma unroll
    for(int nt=0;nt<4;nt++) g[nt] = (v4f){0.f,0.f,0.f,0.f};
    #pragma unroll
    for(int kk=0;kk<2;kk++){
        v8s a = *(const v8s*)&Cb[(w*16+lanelow)*TS + kk*32 + quad*8];
        #pragma unroll
        for(int nt=0;nt<4;nt++){
            v8s bb = *(const v8s*)&Bb[(nt*16+lanelow)*TS + kk*32 + quad*8];
            g[nt] = __builtin_amdgcn_mfma_f32_16x16x32_bf16(a, bb, g[nt], 0,0,0);
        }
    }
    float Lrow[4];
    #pragma unroll
    for(int r=0;r<4;r++) Lrow[r] = Ls[w*16 + quad*4 + r];
    #pragma unroll
    for(int nt=0;nt<4;nt++){
        int col = nt*16 + lanelow;
        float Lc = Ls[col], dtc = dts[col];
        #pragma unroll
        for(int r=0;r<4;r++){
            int rowg = w*16 + quad*4 + r;
            float val = (col <= rowg) ? g[nt][r] * __expf(Lrow[r]-Lc) * dtc : 0.f;
            Gbuf[rowg*TS + col] = f2bf(val);
        }
    }
    __syncthreads();
    // ---- Y = G.X ; S = (X^T).(BtW^T) ----
    v4f ya[4], sa[4];
    #pragma unroll
    for(int nt=0;nt<4;nt++){ ya[nt]=(v4f){0.f,0.f,0.f,0.f}; sa[nt]=(v4f){0.f,0.f,0.f,0.f}; }
    #pragma unroll
    for(int kk=0;kk<2;kk++){
        v8s ag = *(const v8s*)&Gbuf[(w*16+lanelow)*TS + kk*32 + quad*8];
        v8s ax = *(const v8s*)&Xt[(w*16+lanelow)*TS + kk*32 + quad*8];
        #pragma unroll
        for(int nt=0;nt<4;nt++){
            v8s bx = *(const v8s*)&Xt[(nt*16+lanelow)*TS + kk*32 + quad*8];
            v8s bw = *(const v8s*)&BtW[(nt*16+lanelow)*TS + kk*32 + quad*8];
            ya[nt] = __builtin_amdgcn_mfma_f32_16x16x32_bf16(ag, bx, ya[nt], 0,0,0);
            sa[nt] = __builtin_amdgcn_mfma_f32_16x16x32_bf16(ax, bw, sa[nt], 0,0,0);
        }
    }
    float Dp = D_param[h];
    #pragma unroll
    for(int nt=0;nt<4;nt++){
        int col = nt*16 + lanelow;
        #pragma unroll
        for(int r=0;r<4;r++){
            int i = w*16 + quad*4 + r;
            float xval = bf2f(Xt[col*TS + i]);
            yw16[((size_t)b*SEQLEN + l0 + i)*DINNER + h*HEADDIM + col] = f2bf(ya[nt][r] + Dp*xval);
            contrib16[(((size_t)bh*NCH + c)*64 + i)*64 + col] = f2bf(sa[nt][r]);
        }
    }
    if(t < Q) Larr[((size_t)bh*NCH + c)*Q + t] = Ls[t];
    if(t == 0) decayArr[bh*NCH + c] = __expf(L63);
}

// ---------------- inter-chunk state scan (bf16 in/out, fp32 accumulate) ----------------
__global__ __launch_bounds__(256) void k_chunk2(const unsigned short* __restrict__ contrib16,
                                                const float* __restrict__ decayArr,
                                                unsigned short* __restrict__ Sb){
    int bh = blockIdx.x >> 4;
    int part = blockIdx.x & 15;
    int e = part*256 + threadIdx.x;
    const size_t base = (size_t)bh*NCH*4096 + e;
    float vals[NCH];
    #pragma unroll
    for(int c=0;c<NCH;c++) vals[c] = bf2f(contrib16[base + (size_t)c*4096]);
    float s = 0.f;
    #pragma unroll
    for(int c=0;c<NCH;c++){
        Sb[base + (size_t)c*4096] = f2bf(s);
        s = fmaf(s, decayArr[bh*NCH + c], vals[c]);
    }
}

// ---------------- fused inter-chunk output + gate + RMSNorm -> bf16 G ----------------
// grid 128 = b(2) x chunk(32) x half(2); 512 threads = 8 waves, wave = head; 32 tokens/block.
__global__ __launch_bounds__(512) void k_tail(
        const unsigned short* __restrict__ Ccv, const unsigned short* __restrict__ Sb,
        const float* __restrict__ Larr, const unsigned short* __restrict__ yw16,
        const unsigned short* __restrict__ zxb, const float* __restrict__ rms_w,
        unsigned short* __restrict__ Gb){
    int blk = blockIdx.x;
    int half = blk & 1, c = (blk>>1) & 31, b = blk >> 6;
    int t = threadIdx.x;
    int h = t >> 6, lane = t & 63;
    int lanelow = lane & 15, quad = lane >> 4;
    int bh = b*NHEADS + h;
    __shared__ float wsum[8][32];
    __shared__ float rstdS[32];
    const unsigned short* Cp = Ccv + ((size_t)b*NCH + c)*4096;
    const unsigned short* Sp = Sb + ((size_t)bh*NCH + c)*4096;
    v8s a[2][2];
    #pragma unroll
    for(int rt=0;rt<2;rt++){
        int row = half*32 + rt*16 + lanelow;
        a[rt][0] = *(const v8s*)(Cp + row*64 + quad*8);
        a[rt][1] = *(const v8s*)(Cp + row*64 + 32 + quad*8);
    }
    v8s s[4][2];
    #pragma unroll
    for(int nt=0;nt<4;nt++){
        s[nt][0] = *(const v8s*)(Sp + (nt*16+lanelow)*64 + quad*8);
        s[nt][1] = *(const v8s*)(Sp + (nt*16+lanelow)*64 + 32 + quad*8);
    }
    float g[2][4][4];
    float sq[2][4];
    const float* Lp = Larr + ((size_t)bh*NCH + c)*Q;
    #pragma unroll
    for(int rt=0;rt<2;rt++){
        float eL[4];
        #pragma unroll
        for(int r=0;r<4;r++) eL[r] = __expf(Lp[half*32 + rt*16 + quad*4 + r]);
        #pragma unroll
        for(int nt=0;nt<4;nt++){
            v4f acc = (v4f){0.f,0.f,0.f,0.f};
            acc = __builtin_amdgcn_mfma_f32_16x16x32_bf16(a[rt][0], s[nt][0], acc, 0,0,0);
            acc = __builtin_amdgcn_mfma_f32_16x16x32_bf16(a[rt][1], s[nt][1], acc, 0,0,0);
            int col = h*HEADDIM + nt*16 + lanelow;
            #pragma unroll
            for(int r=0;r<4;r++){
                int i = half*32 + rt*16 + quad*4 + r;
                size_t tok = (size_t)b*SEQLEN + c*Q + i;
                float yv = acc[r]*eL[r] + bf2f(yw16[tok*DINNER + col]);
                float z  = bf2f(zxb[tok*DINPROJ + col]);
                float gg = yv * (z/(1.f+__expf(-z)));
                g[rt][nt][r] = gg;
                sq[rt][r] = (nt==0 ? gg*gg : sq[rt][r] + gg*gg);
            }
        }
    }
    #pragma unroll
    for(int rt=0;rt<2;rt++)
        #pragma unroll
        for(int r=0;r<4;r++){
            float v = sq[rt][r];
            #pragma unroll
            for(int m=1;m<16;m<<=1) v += __shfl_xor(v, m);
            sq[rt][r] = v;
        }
    if(lanelow==0){
        #pragma unroll
        for(int rt=0;rt<2;rt++)
            #pragma unroll
            for(int r=0;r<4;r++)
                wsum[h][rt*16 + quad*4 + r] = sq[rt][r];
    }
    __syncthreads();
    if(t < 32){
        float tot = 0.f;
        #pragma unroll
        for(int hh=0;hh<8;hh++) tot += wsum[hh][t];
        rstdS[t] = rsqrtf(tot*(1.f/512.f) + 1e-5f);
    }
    __syncthreads();
    #pragma unroll
    for(int rt=0;rt<2;rt++){
        #pragma unroll
        for(int nt=0;nt<4;nt++){
            int col = h*HEADDIM + nt*16 + lanelow;
            float rw = rms_w[col];
            #pragma unroll
            for(int r=0;r<4;r++){
                int i = rt*16 + quad*4 + r;
                Gb[((size_t)b*SEQLEN + c*Q + half*32 + i)*DINNER + col] = f2bf(g[rt][nt][r] * rstdS[i] * rw);
            }
        }
    }
}

extern "C" void kernel_launch(void* const* d_in, const int* in_sizes, int n_in,
                              void* d_out, int out_size, void* d_ws, size_t ws_size,
                              hipStream_t stream) {
    const float* hid     = (const float*)d_in[0];
    const float* norm_w  = (const float*)d_in[1];
    const float* norm_b  = (const float*)d_in[2];
    const float* Win     = (const float*)d_in[3];
    const float* conv_w  = (const float*)d_in[4];
    const float* conv_b  = (const float*)d_in[5];
    const float* dt_bias = (const float*)d_in[6];
    const float* A_log   = (const float*)d_in[7];
    const float* D_param = (const float*)d_in[8];
    const float* rms_w   = (const float*)d_in[9];
    const float* Wout    = (const float*)d_in[10];

    unsigned short* contrib16 = (unsigned short*)d_ws;            // 16*32*4096 bf16
    float* Larr    = (float*)(contrib16 + (size_t)16*NCH*4096);   // 32768 f
    float* decayA  = Larr + (size_t)16*NCH*Q;                     // 512 f
    unsigned short* zxb  = (unsigned short*)(decayA + 512);       // 4096*1160
    unsigned short* yw16 = zxb + (size_t)NTOK*DINPROJ;            // 4096*512
    unsigned short* Sb   = yw16 + (size_t)NTOK*DINNER;            // 16*32*4096
    unsigned short* Ccv  = Sb + (size_t)16*NCH*4096;              // 2*32*4096
    unsigned short* Xb   = Ccv + (size_t)BATCH*NCH*4096;          // 4096*256
    unsigned short* Gb   = Xb + (size_t)NTOK*DMODEL;              // 4096*512
    unsigned short* Wti  = Gb + (size_t)NTOK*DINNER;              // 1216*256
    unsigned short* Wto  = Wti + (size_t)NPAD_IN*DMODEL;          // 256*512

    float* out = (float*)d_out;
    float* res = out + (size_t)NTOK*DMODEL;

    k_prep<<<256 + NPAD_IN/4 + DMODEL/4, 256, 0, stream>>>(hid, norm_w, norm_b, Win, Wout, res, Xb, Wti, Wto);
    k_gemm<1><<<dim3(NTOK/128, NPAD_IN/64), 256, 0, stream>>>(Xb, Wti, nullptr, zxb, DMODEL, DINPROJ);
    k_chunk1<<<BATCH*NHEADS*NCH, 256, 0, stream>>>(zxb, conv_w, conv_b, dt_bias, A_log, D_param,
                                                   yw16, contrib16, Larr, decayA, Ccv);
    k_chunk2<<<256, 256, 0, stream>>>(contrib16, decayA, Sb);
    k_tail<<<BATCH*NCH*2, 512, 0, stream>>>(Ccv, Sb, Larr, yw16, zxb, rms_w, Gb);
    k_gemm<0><<<dim3(NTOK/128, DMODEL/64), 256, 0, stream>>>(Gb, Wto, out, nullptr, DINNER, DMODEL);
}

// Round 12
// 129.442 us; speedup vs baseline: 2.8019x; 1.0722x over previous
//
#include <hip/hip_runtime.h>
#include <hip/hip_bf16.h>

#define BATCH 2
#define SEQLEN 2048
#define DMODEL 256
#define DINNER 512
#define NHEADS 8
#define HEADDIM 64
#define DSTATE 64
#define CONVDIM 640
#define DINPROJ 1160
#define NTOK (BATCH*SEQLEN)
#define Q 64
#define NCH (SEQLEN/Q)
#define NPAD2 1280     // 10*128, zero-padded transposed W_in
#define TS 72          // bf16 MFMA tile stride in chunk1
#define RS3 196        // conv slab stride

typedef short v8s __attribute__((ext_vector_type(8)));
typedef float v4f __attribute__((ext_vector_type(4)));

__device__ __forceinline__ unsigned short f2bf(float f){
    __hip_bfloat16 h = __float2bfloat16(f);
    return *reinterpret_cast<unsigned short*>(&h);
}
__device__ __forceinline__ float bf2f(unsigned short u){
    unsigned int x = ((unsigned int)u) << 16;
    return __uint_as_float(x);
}

// ---------------- prep: LayerNorm (+residual) and weight conversion, block-partitioned ----------------
// grid 640 = 256 (LN) + 320 (Win cvt -> 1280 rows) + 64 (Wout cvt)
__global__ __launch_bounds__(256) void k_prep(
        const float* __restrict__ hid, const float* __restrict__ nw, const float* __restrict__ nb,
        const float* __restrict__ Win, const float* __restrict__ Wout,
        float* __restrict__ res, unsigned short* __restrict__ Xb,
        unsigned short* __restrict__ Wti, unsigned short* __restrict__ Wto){
    int bx = blockIdx.x;
    int t = threadIdx.x;
    if(bx < 256){
        __shared__ float xs[16][DMODEL];
        int tok0 = bx*16;
        for(int i=0;i<16;i++){
            int idx = i*256+t; int j = idx>>8, c = idx&255;
            float v = hid[(size_t)(tok0+j)*DMODEL + c];
            xs[j][c] = v;
            res[(size_t)(tok0+j)*DMODEL + c] = v;
        }
        __syncthreads();
        int g = t>>4, il = t&15;
        float sum=0.f, sumsq=0.f;
        for(int i=0;i<16;i++){ float v = xs[g][il*16+i]; sum += v; sumsq += v*v; }
        #pragma unroll
        for(int m=1;m<16;m<<=1){ sum += __shfl_xor(sum,m); sumsq += __shfl_xor(sumsq,m); }
        float mu   = sum*(1.f/256.f);
        float var  = sumsq*(1.f/256.f) - mu*mu;
        float rstd = rsqrtf(var + 1e-5f);
        for(int i=0;i<16;i++){
            int c = il*16+i;
            xs[g][c] = (xs[g][c]-mu)*rstd*nw[c] + nb[c];
        }
        __syncthreads();
        for(int i=0;i<16;i++){
            int idx = i*256+t; int j = idx>>8, c = idx&255;
            Xb[(size_t)(tok0+j)*DMODEL + c] = f2bf(xs[j][c]);
        }
    } else if(bx < 256 + NPAD2/4){
        int n0 = (bx-256)*4, k = t;
        #pragma unroll
        for(int i=0;i<4;i++){
            int n = n0+i;
            float v = (n < DINPROJ) ? Win[(size_t)k*DINPROJ + n] : 0.f;
            Wti[(size_t)n*DMODEL + k] = f2bf(v);
        }
    } else {
        int n0 = (bx - 256 - NPAD2/4)*4;
        #pragma unroll
        for(int kk=0;kk<2;kk++){
            int k = t + kk*256;
            #pragma unroll
            for(int i=0;i<4;i++){
                int n = n0+i;
                Wto[(size_t)n*DINNER + k] = f2bf(Wout[(size_t)k*DMODEL + n]);
            }
        }
    }
}

// ---------------- in-proj MFMA GEMM: 128x128 tile, 4 waves = 4 quadrants ----------------
// grid (32, 10); K=256. Output bf16 zxb (cols < 1160).
__global__ __launch_bounds__(256) void k_gemm_in(
        const unsigned short* __restrict__ A, const unsigned short* __restrict__ Bt,
        unsigned short* __restrict__ zxb){
    __shared__ __align__(16) unsigned short As[128*32];
    __shared__ __align__(16) unsigned short Bs[128*32];
    int t = threadIdx.x;
    int lane = t & 63, w = t >> 6;
    int lanelow = lane & 15, quad = lane >> 4;
    int tok0 = blockIdx.x * 128;
    int n0   = blockIdx.y * 128;
    int rw = (w & 1) * 64, cw = (w >> 1) * 64;
    v4f acc[4][4];
    #pragma unroll
    for(int mi=0;mi<4;mi++)
        #pragma unroll
        for(int ni=0;ni<4;ni++)
            acc[mi][ni] = (v4f){0.f,0.f,0.f,0.f};
    for(int k0=0; k0<DMODEL; k0+=32){
        __syncthreads();
        #pragma unroll
        for(int cc=0; cc<2; cc++){
            int u = t + cc*256;
            int row = u>>2, off = u&3;
            *(uint4*)&As[row*32 + off*8] = *(const uint4*)(A + (size_t)(tok0+row)*DMODEL + k0 + off*8);
            *(uint4*)&Bs[row*32 + off*8] = *(const uint4*)(Bt + (size_t)(n0+row)*DMODEL + k0 + off*8);
        }
        __syncthreads();
        v8s a[4], b[4];
        #pragma unroll
        for(int mi=0;mi<4;mi++) a[mi] = *(const v8s*)&As[(rw + mi*16 + lanelow)*32 + quad*8];
        #pragma unroll
        for(int ni=0;ni<4;ni++) b[ni] = *(const v8s*)&Bs[(cw + ni*16 + lanelow)*32 + quad*8];
        #pragma unroll
        for(int mi=0;mi<4;mi++)
            #pragma unroll
            for(int ni=0;ni<4;ni++)
                acc[mi][ni] = __builtin_amdgcn_mfma_f32_16x16x32_bf16(a[mi], b[ni], acc[mi][ni], 0,0,0);
    }
    #pragma unroll
    for(int mi=0;mi<4;mi++){
        #pragma unroll
        for(int ni=0;ni<4;ni++){
            int col = n0 + cw + ni*16 + lanelow;
            if(col < DINPROJ){
                #pragma unroll
                for(int r=0;r<4;r++){
                    int row = tok0 + rw + mi*16 + quad*4 + r;
                    zxb[(size_t)row*DINPROJ + col] = f2bf(acc[mi][ni][r]);
                }
            }
        }
    }
}

// ---------------- out-proj MFMA GEMM: 64x64 tile -> grid (64,4) = 256 blocks ----------------
__global__ __launch_bounds__(256) void k_gemm_out(
        const unsigned short* __restrict__ Gb, const unsigned short* __restrict__ Wto,
        float* __restrict__ out){
    __shared__ __align__(16) unsigned short As[64*32];
    __shared__ __align__(16) unsigned short Bs[64*32];
    int t = threadIdx.x;
    int lane = t & 63, w = t >> 6;
    int lanelow = lane & 15, quad = lane >> 4;
    int tok0 = blockIdx.x * 64;
    int n0   = blockIdx.y * 64;
    v4f acc[4];
    #pragma unroll
    for(int ni=0;ni<4;ni++) acc[ni] = (v4f){0.f,0.f,0.f,0.f};
    for(int k0=0; k0<DINNER; k0+=32){
        __syncthreads();
        {
            int row = t>>2, off = t&3;
            *(uint4*)&As[row*32 + off*8] = *(const uint4*)(Gb + (size_t)(tok0+row)*DINNER + k0 + off*8);
            *(uint4*)&Bs[row*32 + off*8] = *(const uint4*)(Wto + (size_t)(n0+row)*DINNER + k0 + off*8);
        }
        __syncthreads();
        v8s a = *(const v8s*)&As[(w*16 + lanelow)*32 + quad*8];
        #pragma unroll
        for(int ni=0;ni<4;ni++){
            v8s b = *(const v8s*)&Bs[(ni*16 + lanelow)*32 + quad*8];
            acc[ni] = __builtin_amdgcn_mfma_f32_16x16x32_bf16(a, b, acc[ni], 0,0,0);
        }
    }
    #pragma unroll
    for(int ni=0;ni<4;ni++){
        int col = n0 + ni*16 + lanelow;
        #pragma unroll
        for(int r=0;r<4;r++){
            int row = tok0 + w*16 + quad*4 + r;
            out[(size_t)row*DMODEL + col] = acc[ni][r];
        }
    }
}

// ---------------- fused conv + chunk-local SSD via MFMA; conv via coalesced LDS slabs ----------------
// grid 512 = b x h x chunk; 256 threads = 4 waves. LDS ~54 KB -> 3 blocks/CU.
__global__ __launch_bounds__(256) void k_chunk1(
        const unsigned short* __restrict__ zxb, const float* __restrict__ conv_w, const float* __restrict__ conv_b,
        const float* __restrict__ dt_bias, const float* __restrict__ A_log, const float* __restrict__ D_param,
        unsigned short* __restrict__ yw16, unsigned short* __restrict__ contrib16,
        float* __restrict__ Larr, float* __restrict__ decayArr, unsigned short* __restrict__ Ccv){
    int blk = blockIdx.x;
    int c = blk & 31, h = (blk>>5)&7, b = blk>>8;
    int t = threadIdx.x;
    int lane = t & 63, w = t >> 6;
    int lanelow = lane & 15, quad = lane >> 4;
    __shared__ __align__(16) unsigned short Cb[64*TS];
    __shared__ __align__(16) unsigned short Bb[64*TS];
    __shared__ __align__(16) unsigned short BtW[64*TS];
    __shared__ __align__(16) unsigned short Xt[64*TS];
    __shared__ __align__(16) unsigned short Gbuf[64*TS];
    __shared__ __align__(16) unsigned short raw[19*RS3];
    __shared__ float Ls[Q], dts[Q], wch[Q];
    int l0 = c*Q;
    int bh = b*NHEADS + h;
    const unsigned short* zbase = zxb + (size_t)(b*SEQLEN + l0)*DINPROJ;
    if(t < Q){
        float v = bf2f(zbase[(size_t)t*DINPROJ + (DINPROJ-NHEADS) + h]) + dt_bias[h];
        float dt = (v > 20.f) ? v : log1pf(__expf(v));
        float A  = -__expf(A_log[h]);
        float ld = dt*A;
        #pragma unroll
        for(int off=1; off<64; off<<=1){
            float u = __shfl_up(ld, off);
            if(lane >= off) ld += u;
        }
        Ls[t] = ld; dts[t] = dt;
    }
    __syncthreads();
    float L63 = Ls[Q-1];
    if(t < Q) wch[t] = __expf(L63 - Ls[t]) * dts[t];
    unsigned short* CcP = Ccv + ((size_t)b*NCH + c)*4096;
    for(int s=0; s<4; s++){
        __syncthreads();
        #pragma unroll
        for(int i=0;i<4;i++){
            int u = t + 256*i;
            if(u < 19*48){
                int row = u/48, seg = u%48;
                int l = l0 + s*16 - 3 + row;
                int gcol = (seg<16) ? (DINNER + h*HEADDIM + seg*4) : (2*DINNER + (seg-16)*4);
                ushort4 v;
                if(l >= 0) v = *(const ushort4*)(zxb + ((size_t)b*SEQLEN + l)*DINPROJ + gcol);
                else { v.x=0; v.y=0; v.z=0; v.w=0; }
                *(ushort4*)&raw[row*RS3 + seg*4] = v;
            }
        }
        __syncthreads();
        #pragma unroll
        for(int i=0;i<3;i++){
            int u = t + 256*i;
            int stl = u & 15, grp = u >> 4;
            int st = s*16 + stl;
            int ch = grp*4;
            float xk[4][4];
            #pragma unroll
            for(int k=0;k<4;k++){
                ushort4 v = *(const ushort4*)&raw[(stl+k)*RS3 + ch];
                xk[k][0]=bf2f(v.x); xk[k][1]=bf2f(v.y); xk[k][2]=bf2f(v.z); xk[k][3]=bf2f(v.w);
            }
            float wst = wch[st];
            #pragma unroll
            for(int j=0;j<4;j++){
                int chj = ch+j;
                int cc = (chj<64) ? (h*HEADDIM + chj) : (448 + chj);
                float4 wv = *(const float4*)&conv_w[cc*4];
                float acc = conv_b[cc] + wv.x*xk[0][j] + wv.y*xk[1][j] + wv.z*xk[2][j] + wv.w*xk[3][j];
                float sv = acc/(1.f+__expf(-acc));
                if(chj < 64){
                    Xt[chj*TS + st] = f2bf(sv);
                } else if(chj < 128){
                    int n = chj-64;
                    Bb[st*TS + n]  = f2bf(sv);
                    BtW[n*TS + st] = f2bf(sv*wst);
                } else {
                    int n = chj-128;
                    unsigned short sb16 = f2bf(sv);
                    Cb[st*TS + n] = sb16;
                    if(h==0) CcP[st*64 + n] = sb16;
                }
            }
        }
    }
    __syncthreads();
    v4f g[4];
    #pragma unroll
    for(int nt=0;nt<4;nt++) g[nt] = (v4f){0.f,0.f,0.f,0.f};
    #pragma unroll
    for(int kk=0;kk<2;kk++){
        v8s a = *(const v8s*)&Cb[(w*16+lanelow)*TS + kk*32 + quad*8];
        #pragma unroll
        for(int nt=0;nt<4;nt++){
            v8s bb = *(const v8s*)&Bb[(nt*16+lanelow)*TS + kk*32 + quad*8];
            g[nt] = __builtin_amdgcn_mfma_f32_16x16x32_bf16(a, bb, g[nt], 0,0,0);
        }
    }
    float Lrow[4];
    #pragma unroll
    for(int r=0;r<4;r++) Lrow[r] = Ls[w*16 + quad*4 + r];
    #pragma unroll
    for(int nt=0;nt<4;nt++){
        int col = nt*16 + lanelow;
        float Lc = Ls[col], dtc = dts[col];
        #pragma unroll
        for(int r=0;r<4;r++){
            int rowg = w*16 + quad*4 + r;
            float val = (col <= rowg) ? g[nt][r] * __expf(Lrow[r]-Lc) * dtc : 0.f;
            Gbuf[rowg*TS + col] = f2bf(val);
        }
    }
    __syncthreads();
    v4f ya[4], sa[4];
    #pragma unroll
    for(int nt=0;nt<4;nt++){ ya[nt]=(v4f){0.f,0.f,0.f,0.f}; sa[nt]=(v4f){0.f,0.f,0.f,0.f}; }
    #pragma unroll
    for(int kk=0;kk<2;kk++){
        v8s ag = *(const v8s*)&Gbuf[(w*16+lanelow)*TS + kk*32 + quad*8];
        v8s ax = *(const v8s*)&Xt[(w*16+lanelow)*TS + kk*32 + quad*8];
        #pragma unroll
        for(int nt=0;nt<4;nt++){
            v8s bx = *(const v8s*)&Xt[(nt*16+lanelow)*TS + kk*32 + quad*8];
            v8s bw = *(const v8s*)&BtW[(nt*16+lanelow)*TS + kk*32 + quad*8];
            ya[nt] = __builtin_amdgcn_mfma_f32_16x16x32_bf16(ag, bx, ya[nt], 0,0,0);
            sa[nt] = __builtin_amdgcn_mfma_f32_16x16x32_bf16(ax, bw, sa[nt], 0,0,0);
        }
    }
    float Dp = D_param[h];
    #pragma unroll
    for(int nt=0;nt<4;nt++){
        int col = nt*16 + lanelow;
        #pragma unroll
        for(int r=0;r<4;r++){
            int i = w*16 + quad*4 + r;
            float xval = bf2f(Xt[col*TS + i]);
            yw16[((size_t)b*SEQLEN + l0 + i)*DINNER + h*HEADDIM + col] = f2bf(ya[nt][r] + Dp*xval);
            contrib16[(((size_t)bh*NCH + c)*64 + i)*64 + col] = f2bf(sa[nt][r]);
        }
    }
    if(t < Q) Larr[((size_t)bh*NCH + c)*Q + t] = Ls[t];
    if(t == 0) decayArr[bh*NCH + c] = __expf(L63);
}

// ---------------- inter-chunk state scan (bf16 in/out, fp32 accumulate) ----------------
__global__ __launch_bounds__(256) void k_chunk2(const unsigned short* __restrict__ contrib16,
                                                const float* __restrict__ decayArr,
                                                unsigned short* __restrict__ Sb){
    int bh = blockIdx.x >> 4;
    int part = blockIdx.x & 15;
    int e = part*256 + threadIdx.x;
    const size_t base = (size_t)bh*NCH*4096 + e;
    float vals[NCH];
    #pragma unroll
    for(int c=0;c<NCH;c++) vals[c] = bf2f(contrib16[base + (size_t)c*4096]);
    float s = 0.f;
    #pragma unroll
    for(int c=0;c<NCH;c++){
        Sb[base + (size_t)c*4096] = f2bf(s);
        s = fmaf(s, decayArr[bh*NCH + c], vals[c]);
    }
}

// ---------------- fused inter-chunk output + gate + RMSNorm -> bf16 G ----------------
// grid 256 = b(2) x chunk(32) x quarter(4); 512 threads = 8 waves, wave = head; 16 tokens/block.
__global__ __launch_bounds__(512) void k_tail(
        const unsigned short* __restrict__ Ccv, const unsigned short* __restrict__ Sb,
        const float* __restrict__ Larr, const unsigned short* __restrict__ yw16,
        const unsigned short* __restrict__ zxb, const float* __restrict__ rms_w,
        unsigned short* __restrict__ Gb){
    int blk = blockIdx.x;
    int q4 = blk & 3, c = (blk>>2) & 31, b = blk >> 7;
    int t = threadIdx.x;
    int h = t >> 6, lane = t & 63;
    int lanelow = lane & 15, quad = lane >> 4;
    int bh = b*NHEADS + h;
    __shared__ float wsum[8][16];
    __shared__ float rstdS[16];
    const unsigned short* Cp = Ccv + ((size_t)b*NCH + c)*4096;
    const unsigned short* Sp = Sb + ((size_t)bh*NCH + c)*4096;
    int row0 = q4*16;
    v8s a0 = *(const v8s*)(Cp + (row0+lanelow)*64 + quad*8);
    v8s a1 = *(const v8s*)(Cp + (row0+lanelow)*64 + 32 + quad*8);
    v8s s[4][2];
    #pragma unroll
    for(int nt=0;nt<4;nt++){
        s[nt][0] = *(const v8s*)(Sp + (nt*16+lanelow)*64 + quad*8);
        s[nt][1] = *(const v8s*)(Sp + (nt*16+lanelow)*64 + 32 + quad*8);
    }
    float g[4][4];
    float sq[4] = {0.f,0.f,0.f,0.f};
    const float* Lp = Larr + ((size_t)bh*NCH + c)*Q;
    float eL[4];
    #pragma unroll
    for(int r=0;r<4;r++) eL[r] = __expf(Lp[row0 + quad*4 + r]);
    #pragma unroll
    for(int nt=0;nt<4;nt++){
        v4f acc = (v4f){0.f,0.f,0.f,0.f};
        acc = __builtin_amdgcn_mfma_f32_16x16x32_bf16(a0, s[nt][0], acc, 0,0,0);
        acc = __builtin_amdgcn_mfma_f32_16x16x32_bf16(a1, s[nt][1], acc, 0,0,0);
        int col = h*HEADDIM + nt*16 + lanelow;
        #pragma unroll
        for(int r=0;r<4;r++){
            int i = row0 + quad*4 + r;
            size_t tok = (size_t)b*SEQLEN + c*Q + i;
            float yv = acc[r]*eL[r] + bf2f(yw16[tok*DINNER + col]);
            float z  = bf2f(zxb[tok*DINPROJ + col]);
            float gg = yv * (z/(1.f+__expf(-z)));
            g[nt][r] = gg;
            sq[r] += gg*gg;
        }
    }
    #pragma unroll
    for(int r=0;r<4;r++){
        float v = sq[r];
        #pragma unroll
        for(int m=1;m<16;m<<=1) v += __shfl_xor(v, m);
        sq[r] = v;
    }
    if(lanelow==0){
        #pragma unroll
        for(int r=0;r<4;r++) wsum[h][quad*4 + r] = sq[r];
    }
    __syncthreads();
    if(t < 16){
        float tot = 0.f;
        #pragma unroll
        for(int hh=0;hh<8;hh++) tot += wsum[hh][t];
        rstdS[t] = rsqrtf(tot*(1.f/512.f) + 1e-5f);
    }
    __syncthreads();
    #pragma unroll
    for(int nt=0;nt<4;nt++){
        int col = h*HEADDIM + nt*16 + lanelow;
        float rw = rms_w[col];
        #pragma unroll
        for(int r=0;r<4;r++){
            int i = row0 + quad*4 + r;
            Gb[((size_t)b*SEQLEN + c*Q + i)*DINNER + col] = f2bf(g[nt][r] * rstdS[quad*4 + r] * rw);
        }
    }
}

extern "C" void kernel_launch(void* const* d_in, const int* in_sizes, int n_in,
                              void* d_out, int out_size, void* d_ws, size_t ws_size,
                              hipStream_t stream) {
    const float* hid     = (const float*)d_in[0];
    const float* norm_w  = (const float*)d_in[1];
    const float* norm_b  = (const float*)d_in[2];
    const float* Win     = (const float*)d_in[3];
    const float* conv_w  = (const float*)d_in[4];
    const float* conv_b  = (const float*)d_in[5];
    const float* dt_bias = (const float*)d_in[6];
    const float* A_log   = (const float*)d_in[7];
    const float* D_param = (const float*)d_in[8];
    const float* rms_w   = (const float*)d_in[9];
    const float* Wout    = (const float*)d_in[10];

    unsigned short* contrib16 = (unsigned short*)d_ws;            // 16*32*4096 bf16
    float* Larr    = (float*)(contrib16 + (size_t)16*NCH*4096);   // 32768 f
    float* decayA  = Larr + (size_t)16*NCH*Q;                     // 512 f
    unsigned short* zxb  = (unsigned short*)(decayA + 512);       // 4096*1160
    unsigned short* yw16 = zxb + (size_t)NTOK*DINPROJ;            // 4096*512
    unsigned short* Sb   = yw16 + (size_t)NTOK*DINNER;            // 16*32*4096
    unsigned short* Ccv  = Sb + (size_t)16*NCH*4096;              // 2*32*4096
    unsigned short* Xb   = Ccv + (size_t)BATCH*NCH*4096;          // 4096*256
    unsigned short* Gb   = Xb + (size_t)NTOK*DMODEL;              // 4096*512
    unsigned short* Wti  = Gb + (size_t)NTOK*DINNER;              // 1280*256
    unsigned short* Wto  = Wti + (size_t)NPAD2*DMODEL;            // 256*512

    float* out = (float*)d_out;
    float* res = out + (size_t)NTOK*DMODEL;

    k_prep<<<256 + NPAD2/4 + DMODEL/4, 256, 0, stream>>>(hid, norm_w, norm_b, Win, Wout, res, Xb, Wti, Wto);
    k_gemm_in<<<dim3(NTOK/128, NPAD2/128), 256, 0, stream>>>(Xb, Wti, zxb);
    k_chunk1<<<BATCH*NHEADS*NCH, 256, 0, stream>>>(zxb, conv_w, conv_b, dt_bias, A_log, D_param,
                                                   yw16, contrib16, Larr, decayA, Ccv);
    k_chunk2<<<256, 256, 0, stream>>>(contrib16, decayA, Sb);
    k_tail<<<BATCH*NCH*4, 512, 0, stream>>>(Ccv, Sb, Larr, yw16, zxb, rms_w, Gb);
    k_gemm_out<<<dim3(NTOK/64, DMODEL/64), 256, 0, stream>>>(Gb, Wto, out);
}

// Round 13
// 129.016 us; speedup vs baseline: 2.8111x; 1.0033x over previous
//
#include <hip/hip_runtime.h>
#include <hip/hip_bf16.h>

#define BATCH 2
#define SEQLEN 2048
#define DMODEL 256
#define DINNER 512
#define NHEADS 8
#define HEADDIM 64
#define DSTATE 64
#define CONVDIM 640
#define DINPROJ 1160
#define NTOK (BATCH*SEQLEN)
#define Q 64
#define NCH (SEQLEN/Q)
#define NPAD2 1280     // 10*128, zero-padded transposed W_in
#define TS 72          // bf16 MFMA tile stride in chunk1
#define RS3 196        // conv slab stride

typedef short v8s __attribute__((ext_vector_type(8)));
typedef float v4f __attribute__((ext_vector_type(4)));

__device__ __forceinline__ unsigned short f2bf(float f){
    __hip_bfloat16 h = __float2bfloat16(f);
    return *reinterpret_cast<unsigned short*>(&h);
}
__device__ __forceinline__ float bf2f(unsigned short u){
    unsigned int x = ((unsigned int)u) << 16;
    return __uint_as_float(x);
}

// ---------------- prep: LayerNorm (+residual) and weight conversion, block-partitioned ----------------
// grid 640 = 256 (LN) + 320 (Win cvt -> 1280 rows) + 64 (Wout cvt, rms_w folded)
__global__ __launch_bounds__(256) void k_prep(
        const float* __restrict__ hid, const float* __restrict__ nw, const float* __restrict__ nb,
        const float* __restrict__ Win, const float* __restrict__ Wout, const float* __restrict__ rms_w,
        float* __restrict__ res, unsigned short* __restrict__ Xb,
        unsigned short* __restrict__ Wti, unsigned short* __restrict__ Wto){
    int bx = blockIdx.x;
    int t = threadIdx.x;
    if(bx < 256){
        __shared__ float xs[16][DMODEL];
        int tok0 = bx*16;
        for(int i=0;i<16;i++){
            int idx = i*256+t; int j = idx>>8, c = idx&255;
            float v = hid[(size_t)(tok0+j)*DMODEL + c];
            xs[j][c] = v;
            res[(size_t)(tok0+j)*DMODEL + c] = v;
        }
        __syncthreads();
        int g = t>>4, il = t&15;
        float sum=0.f, sumsq=0.f;
        for(int i=0;i<16;i++){ float v = xs[g][il*16+i]; sum += v; sumsq += v*v; }
        #pragma unroll
        for(int m=1;m<16;m<<=1){ sum += __shfl_xor(sum,m); sumsq += __shfl_xor(sumsq,m); }
        float mu   = sum*(1.f/256.f);
        float var  = sumsq*(1.f/256.f) - mu*mu;
        float rstd = rsqrtf(var + 1e-5f);
        for(int i=0;i<16;i++){
            int c = il*16+i;
            xs[g][c] = (xs[g][c]-mu)*rstd*nw[c] + nb[c];
        }
        __syncthreads();
        for(int i=0;i<16;i++){
            int idx = i*256+t; int j = idx>>8, c = idx&255;
            Xb[(size_t)(tok0+j)*DMODEL + c] = f2bf(xs[j][c]);
        }
    } else if(bx < 256 + NPAD2/4){
        int n0 = (bx-256)*4, k = t;
        #pragma unroll
        for(int i=0;i<4;i++){
            int n = n0+i;
            float v = (n < DINPROJ) ? Win[(size_t)k*DINPROJ + n] : 0.f;
            Wti[(size_t)n*DMODEL + k] = f2bf(v);
        }
    } else {
        int n0 = (bx - 256 - NPAD2/4)*4;
        #pragma unroll
        for(int kk=0;kk<2;kk++){
            int k = t + kk*256;
            float rw = rms_w[k];
            #pragma unroll
            for(int i=0;i<4;i++){
                int n = n0+i;
                Wto[(size_t)n*DINNER + k] = f2bf(Wout[(size_t)k*DMODEL + n] * rw);
            }
        }
    }
}

// ---------------- in-proj MFMA GEMM: 128x128 tile, 4 waves = 4 quadrants ----------------
__global__ __launch_bounds__(256) void k_gemm_in(
        const unsigned short* __restrict__ A, const unsigned short* __restrict__ Bt,
        unsigned short* __restrict__ zxb){
    __shared__ __align__(16) unsigned short As[128*32];
    __shared__ __align__(16) unsigned short Bs[128*32];
    int t = threadIdx.x;
    int lane = t & 63, w = t >> 6;
    int lanelow = lane & 15, quad = lane >> 4;
    int tok0 = blockIdx.x * 128;
    int n0   = blockIdx.y * 128;
    int rw = (w & 1) * 64, cw = (w >> 1) * 64;
    v4f acc[4][4];
    #pragma unroll
    for(int mi=0;mi<4;mi++)
        #pragma unroll
        for(int ni=0;ni<4;ni++)
            acc[mi][ni] = (v4f){0.f,0.f,0.f,0.f};
    for(int k0=0; k0<DMODEL; k0+=32){
        __syncthreads();
        #pragma unroll
        for(int cc=0; cc<2; cc++){
            int u = t + cc*256;
            int row = u>>2, off = u&3;
            *(uint4*)&As[row*32 + off*8] = *(const uint4*)(A + (size_t)(tok0+row)*DMODEL + k0 + off*8);
            *(uint4*)&Bs[row*32 + off*8] = *(const uint4*)(Bt + (size_t)(n0+row)*DMODEL + k0 + off*8);
        }
        __syncthreads();
        v8s a[4], b[4];
        #pragma unroll
        for(int mi=0;mi<4;mi++) a[mi] = *(const v8s*)&As[(rw + mi*16 + lanelow)*32 + quad*8];
        #pragma unroll
        for(int ni=0;ni<4;ni++) b[ni] = *(const v8s*)&Bs[(cw + ni*16 + lanelow)*32 + quad*8];
        #pragma unroll
        for(int mi=0;mi<4;mi++)
            #pragma unroll
            for(int ni=0;ni<4;ni++)
                acc[mi][ni] = __builtin_amdgcn_mfma_f32_16x16x32_bf16(a[mi], b[ni], acc[mi][ni], 0,0,0);
    }
    #pragma unroll
    for(int mi=0;mi<4;mi++){
        #pragma unroll
        for(int ni=0;ni<4;ni++){
            int col = n0 + cw + ni*16 + lanelow;
            if(col < DINPROJ){
                #pragma unroll
                for(int r=0;r<4;r++){
                    int row = tok0 + rw + mi*16 + quad*4 + r;
                    zxb[(size_t)row*DINPROJ + col] = f2bf(acc[mi][ni][r]);
                }
            }
        }
    }
}

// ---------------- fused conv + chunk-local SSD via MFMA; conv via coalesced LDS slabs ----------------
__global__ __launch_bounds__(256) void k_chunk1(
        const unsigned short* __restrict__ zxb, const float* __restrict__ conv_w, const float* __restrict__ conv_b,
        const float* __restrict__ dt_bias, const float* __restrict__ A_log, const float* __restrict__ D_param,
        unsigned short* __restrict__ yw16, unsigned short* __restrict__ contrib16,
        float* __restrict__ Larr, float* __restrict__ decayArr, unsigned short* __restrict__ Ccv){
    int blk = blockIdx.x;
    int c = blk & 31, h = (blk>>5)&7, b = blk>>8;
    int t = threadIdx.x;
    int lane = t & 63, w = t >> 6;
    int lanelow = lane & 15, quad = lane >> 4;
    __shared__ __align__(16) unsigned short Cb[64*TS];
    __shared__ __align__(16) unsigned short Bb[64*TS];
    __shared__ __align__(16) unsigned short BtW[64*TS];
    __shared__ __align__(16) unsigned short Xt[64*TS];
    __shared__ __align__(16) unsigned short Gbuf[64*TS];
    __shared__ __align__(16) unsigned short raw[19*RS3];
    __shared__ float Ls[Q], dts[Q], wch[Q];
    int l0 = c*Q;
    int bh = b*NHEADS + h;
    const unsigned short* zbase = zxb + (size_t)(b*SEQLEN + l0)*DINPROJ;
    if(t < Q){
        float v = bf2f(zbase[(size_t)t*DINPROJ + (DINPROJ-NHEADS) + h]) + dt_bias[h];
        float dt = (v > 20.f) ? v : log1pf(__expf(v));
        float A  = -__expf(A_log[h]);
        float ld = dt*A;
        #pragma unroll
        for(int off=1; off<64; off<<=1){
            float u = __shfl_up(ld, off);
            if(lane >= off) ld += u;
        }
        Ls[t] = ld; dts[t] = dt;
    }
    __syncthreads();
    float L63 = Ls[Q-1];
    if(t < Q) wch[t] = __expf(L63 - Ls[t]) * dts[t];
    unsigned short* CcP = Ccv + ((size_t)b*NCH + c)*4096;
    for(int s=0; s<4; s++){
        __syncthreads();
        #pragma unroll
        for(int i=0;i<4;i++){
            int u = t + 256*i;
            if(u < 19*48){
                int row = u/48, seg = u%48;
                int l = l0 + s*16 - 3 + row;
                int gcol = (seg<16) ? (DINNER + h*HEADDIM + seg*4) : (2*DINNER + (seg-16)*4);
                ushort4 v;
                if(l >= 0) v = *(const ushort4*)(zxb + ((size_t)b*SEQLEN + l)*DINPROJ + gcol);
                else { v.x=0; v.y=0; v.z=0; v.w=0; }
                *(ushort4*)&raw[row*RS3 + seg*4] = v;
            }
        }
        __syncthreads();
        #pragma unroll
        for(int i=0;i<3;i++){
            int u = t + 256*i;
            int stl = u & 15, grp = u >> 4;
            int st = s*16 + stl;
            int ch = grp*4;
            float xk[4][4];
            #pragma unroll
            for(int k=0;k<4;k++){
                ushort4 v = *(const ushort4*)&raw[(stl+k)*RS3 + ch];
                xk[k][0]=bf2f(v.x); xk[k][1]=bf2f(v.y); xk[k][2]=bf2f(v.z); xk[k][3]=bf2f(v.w);
            }
            float wst = wch[st];
            #pragma unroll
            for(int j=0;j<4;j++){
                int chj = ch+j;
                int cc = (chj<64) ? (h*HEADDIM + chj) : (448 + chj);
                float4 wv = *(const float4*)&conv_w[cc*4];
                float acc = conv_b[cc] + wv.x*xk[0][j] + wv.y*xk[1][j] + wv.z*xk[2][j] + wv.w*xk[3][j];
                float sv = acc/(1.f+__expf(-acc));
                if(chj < 64){
                    Xt[chj*TS + st] = f2bf(sv);
                } else if(chj < 128){
                    int n = chj-64;
                    Bb[st*TS + n]  = f2bf(sv);
                    BtW[n*TS + st] = f2bf(sv*wst);
                } else {
                    int n = chj-128;
                    unsigned short sb16 = f2bf(sv);
                    Cb[st*TS + n] = sb16;
                    if(h==0) CcP[st*64 + n] = sb16;
                }
            }
        }
    }
    __syncthreads();
    v4f g[4];
    #pragma unroll
    for(int nt=0;nt<4;nt++) g[nt] = (v4f){0.f,0.f,0.f,0.f};
    #pragma unroll
    for(int kk=0;kk<2;kk++){
        v8s a = *(const v8s*)&Cb[(w*16+lanelow)*TS + kk*32 + quad*8];
        #pragma unroll
        for(int nt=0;nt<4;nt++){
            v8s bb = *(const v8s*)&Bb[(nt*16+lanelow)*TS + kk*32 + quad*8];
            g[nt] = __builtin_amdgcn_mfma_f32_16x16x32_bf16(a, bb, g[nt], 0,0,0);
        }
    }
    float Lrow[4];
    #pragma unroll
    for(int r=0;r<4;r++) Lrow[r] = Ls[w*16 + quad*4 + r];
    #pragma unroll
    for(int nt=0;nt<4;nt++){
        int col = nt*16 + lanelow;
        float Lc = Ls[col], dtc = dts[col];
        #pragma unroll
        for(int r=0;r<4;r++){
            int rowg = w*16 + quad*4 + r;
            float val = (col <= rowg) ? g[nt][r] * __expf(Lrow[r]-Lc) * dtc : 0.f;
            Gbuf[rowg*TS + col] = f2bf(val);
        }
    }
    __syncthreads();
    v4f ya[4], sa[4];
    #pragma unroll
    for(int nt=0;nt<4;nt++){ ya[nt]=(v4f){0.f,0.f,0.f,0.f}; sa[nt]=(v4f){0.f,0.f,0.f,0.f}; }
    #pragma unroll
    for(int kk=0;kk<2;kk++){
        v8s ag = *(const v8s*)&Gbuf[(w*16+lanelow)*TS + kk*32 + quad*8];
        v8s ax = *(const v8s*)&Xt[(w*16+lanelow)*TS + kk*32 + quad*8];
        #pragma unroll
        for(int nt=0;nt<4;nt++){
            v8s bx = *(const v8s*)&Xt[(nt*16+lanelow)*TS + kk*32 + quad*8];
            v8s bw = *(const v8s*)&BtW[(nt*16+lanelow)*TS + kk*32 + quad*8];
            ya[nt] = __builtin_amdgcn_mfma_f32_16x16x32_bf16(ag, bx, ya[nt], 0,0,0);
            sa[nt] = __builtin_amdgcn_mfma_f32_16x16x32_bf16(ax, bw, sa[nt], 0,0,0);
        }
    }
    float Dp = D_param[h];
    #pragma unroll
    for(int nt=0;nt<4;nt++){
        int col = nt*16 + lanelow;
        #pragma unroll
        for(int r=0;r<4;r++){
            int i = w*16 + quad*4 + r;
            float xval = bf2f(Xt[col*TS + i]);
            yw16[((size_t)b*SEQLEN + l0 + i)*DINNER + h*HEADDIM + col] = f2bf(ya[nt][r] + Dp*xval);
            contrib16[(((size_t)bh*NCH + c)*64 + i)*64 + col] = f2bf(sa[nt][r]);
        }
    }
    if(t < Q) Larr[((size_t)bh*NCH + c)*Q + t] = Ls[t];
    if(t == 0) decayArr[bh*NCH + c] = __expf(L63);
}

// ---------------- inter-chunk state scan (bf16 in/out, fp32 accumulate) ----------------
__global__ __launch_bounds__(256) void k_chunk2(const unsigned short* __restrict__ contrib16,
                                                const float* __restrict__ decayArr,
                                                unsigned short* __restrict__ Sb){
    int bh = blockIdx.x >> 4;
    int part = blockIdx.x & 15;
    int e = part*256 + threadIdx.x;
    const size_t base = (size_t)bh*NCH*4096 + e;
    float vals[NCH];
    #pragma unroll
    for(int c=0;c<NCH;c++) vals[c] = bf2f(contrib16[base + (size_t)c*4096]);
    float s = 0.f;
    #pragma unroll
    for(int c=0;c<NCH;c++){
        Sb[base + (size_t)c*4096] = f2bf(s);
        s = fmaf(s, decayArr[bh*NCH + c], vals[c]);
    }
}

// ---------------- fused inter-chunk y + gate + RMS + out-proj -> fp32 out ----------------
// grid 256 = b(2) x chunk(32) x quarter(4); 512 threads = 8 waves, wave = head; 16 tokens/block.
__global__ __launch_bounds__(512) void k_tail(
        const unsigned short* __restrict__ Ccv, const unsigned short* __restrict__ Sb,
        const float* __restrict__ Larr, const unsigned short* __restrict__ yw16,
        const unsigned short* __restrict__ zxb, const unsigned short* __restrict__ Wto,
        float* __restrict__ out){
    int blk = blockIdx.x;
    int q4 = blk & 3, c = (blk>>2) & 31, b = blk >> 7;
    int t = threadIdx.x;
    int h = t >> 6, lane = t & 63;
    int lanelow = lane & 15, quad = lane >> 4;
    int bh = b*NHEADS + h;
    __shared__ __align__(16) unsigned short Gs[16*528];
    __shared__ float wsum[8][16];
    __shared__ float rstdS[16];
    const unsigned short* Cp = Ccv + ((size_t)b*NCH + c)*4096;
    const unsigned short* Sp = Sb + ((size_t)bh*NCH + c)*4096;
    int row0 = q4*16;
    v8s a0 = *(const v8s*)(Cp + (row0+lanelow)*64 + quad*8);
    v8s a1 = *(const v8s*)(Cp + (row0+lanelow)*64 + 32 + quad*8);
    v8s s[4][2];
    #pragma unroll
    for(int nt=0;nt<4;nt++){
        s[nt][0] = *(const v8s*)(Sp + (nt*16+lanelow)*64 + quad*8);
        s[nt][1] = *(const v8s*)(Sp + (nt*16+lanelow)*64 + 32 + quad*8);
    }
    float sq[4] = {0.f,0.f,0.f,0.f};
    const float* Lp = Larr + ((size_t)bh*NCH + c)*Q;
    float eL[4];
    #pragma unroll
    for(int r=0;r<4;r++) eL[r] = __expf(Lp[row0 + quad*4 + r]);
    size_t tok0 = (size_t)b*SEQLEN + c*Q + row0;
    #pragma unroll
    for(int nt=0;nt<4;nt++){
        v4f acc = (v4f){0.f,0.f,0.f,0.f};
        acc = __builtin_amdgcn_mfma_f32_16x16x32_bf16(a0, s[nt][0], acc, 0,0,0);
        acc = __builtin_amdgcn_mfma_f32_16x16x32_bf16(a1, s[nt][1], acc, 0,0,0);
        int col = h*HEADDIM + nt*16 + lanelow;
        #pragma unroll
        for(int r=0;r<4;r++){
            size_t tok = tok0 + quad*4 + r;
            float yv = acc[r]*eL[r] + bf2f(yw16[tok*DINNER + col]);
            float z  = bf2f(zxb[tok*DINPROJ + col]);
            float gg = yv * (z/(1.f+__expf(-z)));
            Gs[(quad*4+r)*528 + col] = f2bf(gg);
            sq[r] += gg*gg;
        }
    }
    #pragma unroll
    for(int r=0;r<4;r++){
        float v = sq[r];
        #pragma unroll
        for(int m=1;m<16;m<<=1) v += __shfl_xor(v, m);
        sq[r] = v;
    }
    if(lanelow==0){
        #pragma unroll
        for(int r=0;r<4;r++) wsum[h][quad*4 + r] = sq[r];
    }
    __syncthreads();
    if(t < 16){
        float tot = 0.f;
        #pragma unroll
        for(int hh=0;hh<8;hh++) tot += wsum[hh][t];
        rstdS[t] = rsqrtf(tot*(1.f/512.f) + 1e-5f);
    }
    __syncthreads();
    // out-proj: wave h computes cols [h*32, h*32+32) for these 16 tokens; K=512
    v4f acc2[2];
    #pragma unroll
    for(int nt=0;nt<2;nt++) acc2[nt] = (v4f){0.f,0.f,0.f,0.f};
    for(int ki=0; ki<16; ki++){
        v8s a = *(const v8s*)&Gs[lanelow*528 + ki*32 + quad*8];
        #pragma unroll
        for(int nt=0;nt<2;nt++){
            v8s bfr = *(const v8s*)(Wto + (size_t)(h*32 + nt*16 + lanelow)*DINNER + ki*32 + quad*8);
            acc2[nt] = __builtin_amdgcn_mfma_f32_16x16x32_bf16(a, bfr, acc2[nt], 0,0,0);
        }
    }
    float rs[4];
    #pragma unroll
    for(int r=0;r<4;r++) rs[r] = rstdS[quad*4 + r];
    #pragma unroll
    for(int nt=0;nt<2;nt++){
        int col = h*32 + nt*16 + lanelow;
        #pragma unroll
        for(int r=0;r<4;r++)
            out[(tok0 + quad*4 + r)*DMODEL + col] = acc2[nt][r]*rs[r];
    }
}

extern "C" void kernel_launch(void* const* d_in, const int* in_sizes, int n_in,
                              void* d_out, int out_size, void* d_ws, size_t ws_size,
                              hipStream_t stream) {
    const float* hid     = (const float*)d_in[0];
    const float* norm_w  = (const float*)d_in[1];
    const float* norm_b  = (const float*)d_in[2];
    const float* Win     = (const float*)d_in[3];
    const float* conv_w  = (const float*)d_in[4];
    const float* conv_b  = (const float*)d_in[5];
    const float* dt_bias = (const float*)d_in[6];
    const float* A_log   = (const float*)d_in[7];
    const float* D_param = (const float*)d_in[8];
    const float* rms_w   = (const float*)d_in[9];
    const float* Wout    = (const float*)d_in[10];

    unsigned short* contrib16 = (unsigned short*)d_ws;            // 16*32*4096 bf16
    float* Larr    = (float*)(contrib16 + (size_t)16*NCH*4096);   // 32768 f
    float* decayA  = Larr + (size_t)16*NCH*Q;                     // 512 f
    unsigned short* zxb  = (unsigned short*)(decayA + 512);       // 4096*1160
    unsigned short* yw16 = zxb + (size_t)NTOK*DINPROJ;            // 4096*512
    unsigned short* Sb   = yw16 + (size_t)NTOK*DINNER;            // 16*32*4096
    unsigned short* Ccv  = Sb + (size_t)16*NCH*4096;              // 2*32*4096
    unsigned short* Xb   = Ccv + (size_t)BATCH*NCH*4096;          // 4096*256
    unsigned short* Wti  = Xb + (size_t)NTOK*DMODEL;              // 1280*256
    unsigned short* Wto  = Wti + (size_t)NPAD2*DMODEL;            // 256*512

    float* out = (float*)d_out;
    float* res = out + (size_t)NTOK*DMODEL;

    k_prep<<<256 + NPAD2/4 + DMODEL/4, 256, 0, stream>>>(hid, norm_w, norm_b, Win, Wout, rms_w, res, Xb, Wti, Wto);
    k_gemm_in<<<dim3(NTOK/128, NPAD2/128), 256, 0, stream>>>(Xb, Wti, zxb);
    k_chunk1<<<BATCH*NHEADS*NCH, 256, 0, stream>>>(zxb, conv_w, conv_b, dt_bias, A_log, D_param,
                                                   yw16, contrib16, Larr, decayA, Ccv);
    k_chunk2<<<256, 256, 0, stream>>>(contrib16, decayA, Sb);
    k_tail<<<BATCH*NCH*4, 512, 0, stream>>>(Ccv, Sb, Larr, yw16, zxb, Wto, out);
}

// Round 14
// 128.986 us; speedup vs baseline: 2.8118x; 1.0002x over previous
//
#include <hip/hip_runtime.h>
#include <hip/hip_bf16.h>

#define BATCH 2
#define SEQLEN 2048
#define DMODEL 256
#define DINNER 512
#define NHEADS 8
#define HEADDIM 64
#define DSTATE 64
#define CONVDIM 640
#define DINPROJ 1160
#define NTOK (BATCH*SEQLEN)
#define Q 64
#define NCH (SEQLEN/Q)
#define NPAD2 1280     // 10*128, zero-padded transposed W_in
#define TS 72          // chunk1 tile stride: word-stride 36 -> bank step 4, 2-way (free)
#define RS3 196        // conv slab stride
#define GS 536         // tail G stride: word-stride 268 -> bank step 12, 2-way (free)
#define AS_STRIDE 40   // gemm_in LDS stride: word-stride 20 -> bank step 20, 2-way (free)

typedef short v8s __attribute__((ext_vector_type(8)));
typedef float v4f __attribute__((ext_vector_type(4)));

__device__ __forceinline__ unsigned short f2bf(float f){
    __hip_bfloat16 h = __float2bfloat16(f);
    return *reinterpret_cast<unsigned short*>(&h);
}
__device__ __forceinline__ float bf2f(unsigned short u){
    unsigned int x = ((unsigned int)u) << 16;
    return __uint_as_float(x);
}

// ---------------- prep: LayerNorm (+residual) and weight conversion, block-partitioned ----------------
__global__ __launch_bounds__(256) void k_prep(
        const float* __restrict__ hid, const float* __restrict__ nw, const float* __restrict__ nb,
        const float* __restrict__ Win, const float* __restrict__ Wout, const float* __restrict__ rms_w,
        float* __restrict__ res, unsigned short* __restrict__ Xb,
        unsigned short* __restrict__ Wti, unsigned short* __restrict__ Wto){
    int bx = blockIdx.x;
    int t = threadIdx.x;
    if(bx < 256){
        __shared__ float xs[16][DMODEL];
        int tok0 = bx*16;
        for(int i=0;i<16;i++){
            int idx = i*256+t; int j = idx>>8, c = idx&255;
            float v = hid[(size_t)(tok0+j)*DMODEL + c];
            xs[j][c] = v;
            res[(size_t)(tok0+j)*DMODEL + c] = v;
        }
        __syncthreads();
        int g = t>>4, il = t&15;
        float sum=0.f, sumsq=0.f;
        for(int i=0;i<16;i++){ float v = xs[g][il*16+i]; sum += v; sumsq += v*v; }
        #pragma unroll
        for(int m=1;m<16;m<<=1){ sum += __shfl_xor(sum,m); sumsq += __shfl_xor(sumsq,m); }
        float mu   = sum*(1.f/256.f);
        float var  = sumsq*(1.f/256.f) - mu*mu;
        float rstd = rsqrtf(var + 1e-5f);
        for(int i=0;i<16;i++){
            int c = il*16+i;
            xs[g][c] = (xs[g][c]-mu)*rstd*nw[c] + nb[c];
        }
        __syncthreads();
        for(int i=0;i<16;i++){
            int idx = i*256+t; int j = idx>>8, c = idx&255;
            Xb[(size_t)(tok0+j)*DMODEL + c] = f2bf(xs[j][c]);
        }
    } else if(bx < 256 + NPAD2/4){
        int n0 = (bx-256)*4, k = t;
        #pragma unroll
        for(int i=0;i<4;i++){
            int n = n0+i;
            float v = (n < DINPROJ) ? Win[(size_t)k*DINPROJ + n] : 0.f;
            Wti[(size_t)n*DMODEL + k] = f2bf(v);
        }
    } else {
        int n0 = (bx - 256 - NPAD2/4)*4;
        #pragma unroll
        for(int kk=0;kk<2;kk++){
            int k = t + kk*256;
            float rw = rms_w[k];
            #pragma unroll
            for(int i=0;i<4;i++){
                int n = n0+i;
                Wto[(size_t)n*DINNER + k] = f2bf(Wout[(size_t)k*DMODEL + n] * rw);
            }
        }
    }
}

// ---------------- in-proj MFMA GEMM: 128x128 tile, 4 waves = 4 quadrants, stride-40 LDS ----------------
__global__ __launch_bounds__(256) void k_gemm_in(
        const unsigned short* __restrict__ A, const unsigned short* __restrict__ Bt,
        unsigned short* __restrict__ zxb){
    __shared__ __align__(16) unsigned short As[128*AS_STRIDE];
    __shared__ __align__(16) unsigned short Bs[128*AS_STRIDE];
    int t = threadIdx.x;
    int lane = t & 63, w = t >> 6;
    int lanelow = lane & 15, quad = lane >> 4;
    int tok0 = blockIdx.x * 128;
    int n0   = blockIdx.y * 128;
    int rw = (w & 1) * 64, cw = (w >> 1) * 64;
    v4f acc[4][4];
    #pragma unroll
    for(int mi=0;mi<4;mi++)
        #pragma unroll
        for(int ni=0;ni<4;ni++)
            acc[mi][ni] = (v4f){0.f,0.f,0.f,0.f};
    for(int k0=0; k0<DMODEL; k0+=32){
        __syncthreads();
        #pragma unroll
        for(int cc=0; cc<2; cc++){
            int u = t + cc*256;
            int row = u>>2, off = u&3;
            *(uint4*)&As[row*AS_STRIDE + off*8] = *(const uint4*)(A + (size_t)(tok0+row)*DMODEL + k0 + off*8);
            *(uint4*)&Bs[row*AS_STRIDE + off*8] = *(const uint4*)(Bt + (size_t)(n0+row)*DMODEL + k0 + off*8);
        }
        __syncthreads();
        v8s a[4], b[4];
        #pragma unroll
        for(int mi=0;mi<4;mi++) a[mi] = *(const v8s*)&As[(rw + mi*16 + lanelow)*AS_STRIDE + quad*8];
        #pragma unroll
        for(int ni=0;ni<4;ni++) b[ni] = *(const v8s*)&Bs[(cw + ni*16 + lanelow)*AS_STRIDE + quad*8];
        #pragma unroll
        for(int mi=0;mi<4;mi++)
            #pragma unroll
            for(int ni=0;ni<4;ni++)
                acc[mi][ni] = __builtin_amdgcn_mfma_f32_16x16x32_bf16(a[mi], b[ni], acc[mi][ni], 0,0,0);
    }
    #pragma unroll
    for(int mi=0;mi<4;mi++){
        #pragma unroll
        for(int ni=0;ni<4;ni++){
            int col = n0 + cw + ni*16 + lanelow;
            if(col < DINPROJ){
                #pragma unroll
                for(int r=0;r<4;r++){
                    int row = tok0 + rw + mi*16 + quad*4 + r;
                    zxb[(size_t)row*DINPROJ + col] = f2bf(acc[mi][ni][r]);
                }
            }
        }
    }
}

// ---------------- fused conv + chunk-local SSD via MFMA; raw/Gbuf aliased -> 3 blocks/CU ----------------
__global__ __launch_bounds__(256) void k_chunk1(
        const unsigned short* __restrict__ zxb, const float* __restrict__ conv_w, const float* __restrict__ conv_b,
        const float* __restrict__ dt_bias, const float* __restrict__ A_log, const float* __restrict__ D_param,
        unsigned short* __restrict__ yw16, unsigned short* __restrict__ contrib16,
        float* __restrict__ Larr, float* __restrict__ decayArr, unsigned short* __restrict__ Ccv){
    int blk = blockIdx.x;
    int c = blk & 31, h = (blk>>5)&7, b = blk>>8;
    int t = threadIdx.x;
    int lane = t & 63, w = t >> 6;
    int lanelow = lane & 15, quad = lane >> 4;
    __shared__ __align__(16) unsigned short Cb[64*TS];
    __shared__ __align__(16) unsigned short Bb[64*TS];
    __shared__ __align__(16) unsigned short BtW[64*TS];
    __shared__ __align__(16) unsigned short Xt[64*TS];
    __shared__ __align__(16) unsigned short GbufRaw[64*TS];  // conv 'raw' (19*196=3724) aliased with Gbuf (4608)
    __shared__ float Ls[Q], dts[Q], wch[Q];
    unsigned short* raw  = GbufRaw;   // live during conv slabs only
    unsigned short* Gbuf = GbufRaw;   // live after conv completes
    int l0 = c*Q;
    int bh = b*NHEADS + h;
    const unsigned short* zbase = zxb + (size_t)(b*SEQLEN + l0)*DINPROJ;
    if(t < Q){
        float v = bf2f(zbase[(size_t)t*DINPROJ + (DINPROJ-NHEADS) + h]) + dt_bias[h];
        float dt = (v > 20.f) ? v : log1pf(__expf(v));
        float A  = -__expf(A_log[h]);
        float ld = dt*A;
        #pragma unroll
        for(int off=1; off<64; off<<=1){
            float u = __shfl_up(ld, off);
            if(lane >= off) ld += u;
        }
        Ls[t] = ld; dts[t] = dt;
    }
    __syncthreads();
    float L63 = Ls[Q-1];
    if(t < Q) wch[t] = __expf(L63 - Ls[t]) * dts[t];
    unsigned short* CcP = Ccv + ((size_t)b*NCH + c)*4096;
    for(int s=0; s<4; s++){
        __syncthreads();
        #pragma unroll
        for(int i=0;i<4;i++){
            int u = t + 256*i;
            if(u < 19*48){
                int row = u/48, seg = u%48;
                int l = l0 + s*16 - 3 + row;
                int gcol = (seg<16) ? (DINNER + h*HEADDIM + seg*4) : (2*DINNER + (seg-16)*4);
                ushort4 v;
                if(l >= 0) v = *(const ushort4*)(zxb + ((size_t)b*SEQLEN + l)*DINPROJ + gcol);
                else { v.x=0; v.y=0; v.z=0; v.w=0; }
                *(ushort4*)&raw[row*RS3 + seg*4] = v;
            }
        }
        __syncthreads();
        #pragma unroll
        for(int i=0;i<3;i++){
            int u = t + 256*i;
            int stl = u & 15, grp = u >> 4;
            int st = s*16 + stl;
            int ch = grp*4;
            float xk[4][4];
            #pragma unroll
            for(int k=0;k<4;k++){
                ushort4 v = *(const ushort4*)&raw[(stl+k)*RS3 + ch];
                xk[k][0]=bf2f(v.x); xk[k][1]=bf2f(v.y); xk[k][2]=bf2f(v.z); xk[k][3]=bf2f(v.w);
            }
            float wst = wch[st];
            #pragma unroll
            for(int j=0;j<4;j++){
                int chj = ch+j;
                int cc = (chj<64) ? (h*HEADDIM + chj) : (448 + chj);
                float4 wv = *(const float4*)&conv_w[cc*4];
                float acc = conv_b[cc] + wv.x*xk[0][j] + wv.y*xk[1][j] + wv.z*xk[2][j] + wv.w*xk[3][j];
                float sv = acc/(1.f+__expf(-acc));
                if(chj < 64){
                    Xt[chj*TS + st] = f2bf(sv);
                } else if(chj < 128){
                    int n = chj-64;
                    Bb[st*TS + n]  = f2bf(sv);
                    BtW[n*TS + st] = f2bf(sv*wst);
                } else {
                    int n = chj-128;
                    unsigned short sb16 = f2bf(sv);
                    Cb[st*TS + n] = sb16;
                    if(h==0) CcP[st*64 + n] = sb16;
                }
            }
        }
    }
    __syncthreads();   // conv fully done: 'raw' dead, 'Gbuf' may now be written
    v4f g[4];
    #pragma unroll
    for(int nt=0;nt<4;nt++) g[nt] = (v4f){0.f,0.f,0.f,0.f};
    #pragma unroll
    for(int kk=0;kk<2;kk++){
        v8s a = *(const v8s*)&Cb[(w*16+lanelow)*TS + kk*32 + quad*8];
        #pragma unroll
        for(int nt=0;nt<4;nt++){
            v8s bb = *(const v8s*)&Bb[(nt*16+lanelow)*TS + kk*32 + quad*8];
            g[nt] = __builtin_amdgcn_mfma_f32_16x16x32_bf16(a, bb, g[nt], 0,0,0);
        }
    }
    float Lrow[4];
    #pragma unroll
    for(int r=0;r<4;r++) Lrow[r] = Ls[w*16 + quad*4 + r];
    #pragma unroll
    for(int nt=0;nt<4;nt++){
        int col = nt*16 + lanelow;
        float Lc = Ls[col], dtc = dts[col];
        #pragma unroll
        for(int r=0;r<4;r++){
            int rowg = w*16 + quad*4 + r;
            float val = (col <= rowg) ? g[nt][r] * __expf(Lrow[r]-Lc) * dtc : 0.f;
            Gbuf[rowg*TS + col] = f2bf(val);
        }
    }
    __syncthreads();
    v4f ya[4], sa[4];
    #pragma unroll
    for(int nt=0;nt<4;nt++){ ya[nt]=(v4f){0.f,0.f,0.f,0.f}; sa[nt]=(v4f){0.f,0.f,0.f,0.f}; }
    #pragma unroll
    for(int kk=0;kk<2;kk++){
        v8s ag = *(const v8s*)&Gbuf[(w*16+lanelow)*TS + kk*32 + quad*8];
        v8s ax = *(const v8s*)&Xt[(w*16+lanelow)*TS + kk*32 + quad*8];
        #pragma unroll
        for(int nt=0;nt<4;nt++){
            v8s bx = *(const v8s*)&Xt[(nt*16+lanelow)*TS + kk*32 + quad*8];
            v8s bw = *(const v8s*)&BtW[(nt*16+lanelow)*TS + kk*32 + quad*8];
            ya[nt] = __builtin_amdgcn_mfma_f32_16x16x32_bf16(ag, bx, ya[nt], 0,0,0);
            sa[nt] = __builtin_amdgcn_mfma_f32_16x16x32_bf16(ax, bw, sa[nt], 0,0,0);
        }
    }
    float Dp = D_param[h];
    #pragma unroll
    for(int nt=0;nt<4;nt++){
        int col = nt*16 + lanelow;
        #pragma unroll
        for(int r=0;r<4;r++){
            int i = w*16 + quad*4 + r;
            float xval = bf2f(Xt[col*TS + i]);
            yw16[((size_t)b*SEQLEN + l0 + i)*DINNER + h*HEADDIM + col] = f2bf(ya[nt][r] + Dp*xval);
            contrib16[(((size_t)bh*NCH + c)*64 + i)*64 + col] = f2bf(sa[nt][r]);
        }
    }
    if(t < Q) Larr[((size_t)bh*NCH + c)*Q + t] = Ls[t];
    if(t == 0) decayArr[bh*NCH + c] = __expf(L63);
}

// ---------------- inter-chunk state scan (bf16 in/out, fp32 accumulate) ----------------
__global__ __launch_bounds__(256) void k_chunk2(const unsigned short* __restrict__ contrib16,
                                                const float* __restrict__ decayArr,
                                                unsigned short* __restrict__ Sb){
    int bh = blockIdx.x >> 4;
    int part = blockIdx.x & 15;
    int e = part*256 + threadIdx.x;
    const size_t base = (size_t)bh*NCH*4096 + e;
    float vals[NCH];
    #pragma unroll
    for(int c=0;c<NCH;c++) vals[c] = bf2f(contrib16[base + (size_t)c*4096]);
    float s = 0.f;
    #pragma unroll
    for(int c=0;c<NCH;c++){
        Sb[base + (size_t)c*4096] = f2bf(s);
        s = fmaf(s, decayArr[bh*NCH + c], vals[c]);
    }
}

// ---------------- fused inter-chunk y + gate + RMS + out-proj -> fp32 out ----------------
__global__ __launch_bounds__(512) void k_tail(
        const unsigned short* __restrict__ Ccv, const unsigned short* __restrict__ Sb,
        const float* __restrict__ Larr, const unsigned short* __restrict__ yw16,
        const unsigned short* __restrict__ zxb, const unsigned short* __restrict__ Wto,
        float* __restrict__ out){
    int blk = blockIdx.x;
    int q4 = blk & 3, c = (blk>>2) & 31, b = blk >> 7;
    int t = threadIdx.x;
    int h = t >> 6, lane = t & 63;
    int lanelow = lane & 15, quad = lane >> 4;
    int bh = b*NHEADS + h;
    __shared__ __align__(16) unsigned short Gs[16*GS];
    __shared__ float wsum[8][16];
    __shared__ float rstdS[16];
    const unsigned short* Cp = Ccv + ((size_t)b*NCH + c)*4096;
    const unsigned short* Sp = Sb + ((size_t)bh*NCH + c)*4096;
    int row0 = q4*16;
    v8s a0 = *(const v8s*)(Cp + (row0+lanelow)*64 + quad*8);
    v8s a1 = *(const v8s*)(Cp + (row0+lanelow)*64 + 32 + quad*8);
    v8s s[4][2];
    #pragma unroll
    for(int nt=0;nt<4;nt++){
        s[nt][0] = *(const v8s*)(Sp + (nt*16+lanelow)*64 + quad*8);
        s[nt][1] = *(const v8s*)(Sp + (nt*16+lanelow)*64 + 32 + quad*8);
    }
    float sq[4] = {0.f,0.f,0.f,0.f};
    const float* Lp = Larr + ((size_t)bh*NCH + c)*Q;
    float eL[4];
    #pragma unroll
    for(int r=0;r<4;r++) eL[r] = __expf(Lp[row0 + quad*4 + r]);
    size_t tok0 = (size_t)b*SEQLEN + c*Q + row0;
    #pragma unroll
    for(int nt=0;nt<4;nt++){
        v4f acc = (v4f){0.f,0.f,0.f,0.f};
        acc = __builtin_amdgcn_mfma_f32_16x16x32_bf16(a0, s[nt][0], acc, 0,0,0);
        acc = __builtin_amdgcn_mfma_f32_16x16x32_bf16(a1, s[nt][1], acc, 0,0,0);
        int col = h*HEADDIM + nt*16 + lanelow;
        #pragma unroll
        for(int r=0;r<4;r++){
            size_t tok = tok0 + quad*4 + r;
            float yv = acc[r]*eL[r] + bf2f(yw16[tok*DINNER + col]);
            float z  = bf2f(zxb[tok*DINPROJ + col]);
            float gg = yv * (z/(1.f+__expf(-z)));
            Gs[(quad*4+r)*GS + col] = f2bf(gg);
            sq[r] += gg*gg;
        }
    }
    #pragma unroll
    for(int r=0;r<4;r++){
        float v = sq[r];
        #pragma unroll
        for(int m=1;m<16;m<<=1) v += __shfl_xor(v, m);
        sq[r] = v;
    }
    if(lanelow==0){
        #pragma unroll
        for(int r=0;r<4;r++) wsum[h][quad*4 + r] = sq[r];
    }
    __syncthreads();
    if(t < 16){
        float tot = 0.f;
        #pragma unroll
        for(int hh=0;hh<8;hh++) tot += wsum[hh][t];
        rstdS[t] = rsqrtf(tot*(1.f/512.f) + 1e-5f);
    }
    __syncthreads();
    // out-proj: wave h computes cols [h*32, h*32+32) for these 16 tokens; K=512
    v4f acc2[2];
    #pragma unroll
    for(int nt=0;nt<2;nt++) acc2[nt] = (v4f){0.f,0.f,0.f,0.f};
    for(int ki=0; ki<16; ki++){
        v8s a = *(const v8s*)&Gs[lanelow*GS + ki*32 + quad*8];
        #pragma unroll
        for(int nt=0;nt<2;nt++){
            v8s bfr = *(const v8s*)(Wto + (size_t)(h*32 + nt*16 + lanelow)*DINNER + ki*32 + quad*8);
            acc2[nt] = __builtin_amdgcn_mfma_f32_16x16x32_bf16(a, bfr, acc2[nt], 0,0,0);
        }
    }
    float rs[4];
    #pragma unroll
    for(int r=0;r<4;r++) rs[r] = rstdS[quad*4 + r];
    #pragma unroll
    for(int nt=0;nt<2;nt++){
        int col = h*32 + nt*16 + lanelow;
        #pragma unroll
        for(int r=0;r<4;r++)
            out[(tok0 + quad*4 + r)*DMODEL + col] = acc2[nt][r]*rs[r];
    }
}

extern "C" void kernel_launch(void* const* d_in, const int* in_sizes, int n_in,
                              void* d_out, int out_size, void* d_ws, size_t ws_size,
                              hipStream_t stream) {
    const float* hid     = (const float*)d_in[0];
    const float* norm_w  = (const float*)d_in[1];
    const float* norm_b  = (const float*)d_in[2];
    const float* Win     = (const float*)d_in[3];
    const float* conv_w  = (const float*)d_in[4];
    const float* conv_b  = (const float*)d_in[5];
    const float* dt_bias = (const float*)d_in[6];
    const float* A_log   = (const float*)d_in[7];
    const float* D_param = (const float*)d_in[8];
    const float* rms_w   = (const float*)d_in[9];
    const float* Wout    = (const float*)d_in[10];

    unsigned short* contrib16 = (unsigned short*)d_ws;            // 16*32*4096 bf16
    float* Larr    = (float*)(contrib16 + (size_t)16*NCH*4096);   // 32768 f
    float* decayA  = Larr + (size_t)16*NCH*Q;                     // 512 f
    unsigned short* zxb  = (unsigned short*)(decayA + 512);       // 4096*1160
    unsigned short* yw16 = zxb + (size_t)NTOK*DINPROJ;            // 4096*512
    unsigned short* Sb   = yw16 + (size_t)NTOK*DINNER;            // 16*32*4096
    unsigned short* Ccv  = Sb + (size_t)16*NCH*4096;              // 2*32*4096
    unsigned short* Xb   = Ccv + (size_t)BATCH*NCH*4096;          // 4096*256
    unsigned short* Wti  = Xb + (size_t)NTOK*DMODEL;              // 1280*256
    unsigned short* Wto  = Wti + (size_t)NPAD2*DMODEL;            // 256*512

    float* out = (float*)d_out;
    float* res = out + (size_t)NTOK*DMODEL;

    k_prep<<<256 + NPAD2/4 + DMODEL/4, 256, 0, stream>>>(hid, norm_w, norm_b, Win, Wout, rms_w, res, Xb, Wti, Wto);
    k_gemm_in<<<dim3(NTOK/128, NPAD2/128), 256, 0, stream>>>(Xb, Wti, zxb);
    k_chunk1<<<BATCH*NHEADS*NCH, 256, 0, stream>>>(zxb, conv_w, conv_b, dt_bias, A_log, D_param,
                                                   yw16, contrib16, Larr, decayA, Ccv);
    k_chunk2<<<256, 256, 0, stream>>>(contrib16, decayA, Sb);
    k_tail<<<BATCH*NCH*4, 512, 0, stream>>>(Ccv, Sb, Larr, yw16, zxb, Wto, out);
}